// Round 12
// baseline (555.967 us; speedup 1.0000x reference)
//
#include <hip/hip_runtime.h>
#include <cstdint>

constexpr int NN   = 30000;
constexpr int NE   = 960000;
constexpr int FIN  = 16;
constexpr int H1   = 36;
constexpr int H2   = 36;
constexpr int KHOP = 8;
constexpr int KSEL = 3000;   // ceil(0.1 * 30000)
constexpr int PCAP = 32768;  // pooled-edge capacity (expected ~9600)
constexpr int NCHUNK = 12;   // candidate chunks for nearest (3000/12 = 250)
constexpr int CHUNK = KSEL / NCHUNK;
constexpr int NB_H = 32;     // histogram blocks
constexpr int EPB  = (NE + NB_H - 1) / NB_H;   // edges per histogram block (30000)
constexpr float EPSV = 1e-5f;

#define TPB 256

static inline int nb(long long t) { return (int)((t + TPB - 1) / TPB); }

// ---------------- LDS histogram: partials[y][b][j]; dst pass also records rank ----------------
__global__ __launch_bounds__(1024)
void k_hist(const int* __restrict__ src, const int* __restrict__ dst,
            int* __restrict__ partials, int* __restrict__ rank) {
    __shared__ int hist[NN];   // 120 KB
    for (int j = threadIdx.x; j < NN; j += 1024) hist[j] = 0;
    __syncthreads();
    int b = blockIdx.x;
    int e0 = b * EPB, e1 = min(NE, e0 + EPB);
    if (blockIdx.y == 0) {
        for (int e = e0 + (int)threadIdx.x; e < e1; e += 1024)
            atomicAdd(&hist[src[e]], 1);
    } else {
        for (int e = e0 + (int)threadIdx.x; e < e1; e += 1024)
            rank[e] = atomicAdd(&hist[dst[e]], 1);
    }
    __syncthreads();
    int* P = partials + ((size_t)blockIdx.y * NB_H + b) * NN;
    for (int j = threadIdx.x; j < NN; j += 1024) P[j] = hist[j];
}

// ---------------- reduce partials: dinv (src), per-block exclusive offsets + cnt_dst
//                   also zeroes the BN-stats buffer (144 floats) ----------------
__global__ void k_red(int* __restrict__ partials, float* __restrict__ dinv,
                      int* __restrict__ cnt_dst, float* __restrict__ stats) {
    if (blockIdx.x == 0 && threadIdx.x < 144) stats[threadIdx.x] = 0.f;
    int j = blockIdx.x * blockDim.x + threadIdx.x;
    if (j >= NN) return;
    const int* Ps = partials;
    int s = 0;
#pragma unroll
    for (int b = 0; b < NB_H; ++b) s += Ps[(size_t)b * NN + j];
    dinv[j] = s > 0 ? rsqrtf((float)s) : 0.0f;
    int* Pd = partials + (size_t)NB_H * NN;
    int run = 0;
#pragma unroll
    for (int b = 0; b < NB_H; ++b) {
        int t = Pd[(size_t)b * NN + j];
        Pd[(size_t)b * NN + j] = run;
        run += t;
    }
    cnt_dst[j] = run;
}

// ---------------- block scan helper (blockDim must be 1024) ----------------
__device__ __forceinline__ int block_scan_excl_1024(int val, int& total) {
    __shared__ int wsum[16];
    int tid = threadIdx.x, lane = tid & 63, wv = tid >> 6;
    int v = val;
#pragma unroll
    for (int off = 1; off < 64; off <<= 1) {
        int t = __shfl_up(v, off, 64);
        if (lane >= off) v += t;
    }
    __syncthreads();
    if (lane == 63) wsum[wv] = v;
    __syncthreads();
    if (tid < 16) {
        int w = wsum[tid];
#pragma unroll
        for (int off = 1; off < 16; off <<= 1) {
            int t = __shfl_up(w, off, 64);
            if (tid >= off) w += t;
        }
        wsum[tid] = w;
    }
    __syncthreads();
    int base = (wv > 0) ? wsum[wv - 1] : 0;
    total = wsum[15];
    return base + v - val;
}

__global__ void k_scan(const int* __restrict__ cnt, int* __restrict__ rowstart, int n) {
    __shared__ int run;
    if (threadIdx.x == 0) run = 0;
    __syncthreads();
    for (int base = 0; base < n; base += 1024) {
        int i = base + threadIdx.x;
        int v = (i < n) ? cnt[i] : 0;
        int tot; int ex = block_scan_excl_1024(v, tot);
        int r = run;
        if (i < n) rowstart[i] = r + ex;
        __syncthreads();
        if (threadIdx.x == 0) run += tot;
        __syncthreads();
    }
    if (threadIdx.x == 0) rowstart[n] = run;
}

// scan for pooled lens (n = KSEL) + fused pooled dinv from pcnt
__global__ __launch_bounds__(1024)
void k_scan_pool(const int* __restrict__ lens, int* __restrict__ prs,
                 const int* __restrict__ pcnt, float* __restrict__ dinvp) {
    __shared__ int run;
    if (threadIdx.x == 0) run = 0;
    __syncthreads();
    for (int base = 0; base < KSEL; base += 1024) {
        int i = base + threadIdx.x;
        int v = (i < KSEL) ? lens[i] : 0;
        int tot; int ex = block_scan_excl_1024(v, tot);
        int r = run;
        if (i < KSEL) prs[i] = r + ex;
        __syncthreads();
        if (threadIdx.x == 0) run += tot;
        __syncthreads();
    }
    if (threadIdx.x == 0) prs[KSEL] = run;
    for (int j = threadIdx.x; j < KSEL; j += 1024) {
        int c = pcnt[j];
        dinvp[j] = c > 0 ? rsqrtf((float)c) : 0.0f;
    }
}

// ---------------- CSR fill: pure function of precomputed rank (no atomics, no LDS) ----------------
__global__ void k_fill3(const int* __restrict__ src, const int* __restrict__ dst,
                        const int* __restrict__ rank, const float* __restrict__ dinv,
                        const int* __restrict__ rowstart, const int* __restrict__ Pd_excl,
                        int2* __restrict__ csr, int E) {
    int e = blockIdx.x * blockDim.x + threadIdx.x;
    if (e >= E) return;
    int s = src[e], d = dst[e];
    int b = e / EPB;
    int pos = rowstart[d] + Pd_excl[(size_t)b * NN + d] + rank[e];
    float w = -dinv[s] * dinv[d];
    csr[pos] = make_int2(s, __float_as_int(w));
}

// ---------------- fused prop+GEMM, edge-split ES, optional first-hop W0 fusion ----------------
// FIRST: t1 = A^ h ; acc = bias + h@W0 + t1@Wk   (t0 unused)
// else : t_k = 2*A^ h - t0 ; acc += t_k@Wk
template<int F, int O, int BN, int ES, bool FIRST>
__global__ __launch_bounds__(BN * (F / 4) * ES)
void k_prop_gemm(const int* __restrict__ rowstart, const int2* __restrict__ csr,
                 const float* __restrict__ h, const float* __restrict__ t0,
                 const float* __restrict__ Wk, const float* __restrict__ W0,
                 const float* __restrict__ bias, float* __restrict__ tout,
                 float* __restrict__ acc, int n) {
    constexpr int QF = F / 4;
    constexpr int NTH = BN * QF;
    constexpr int NT = NTH * ES;
    __shared__ float sT[BN * F];
    __shared__ float sP[(ES > 1) ? BN * F : 1];
    __shared__ float sW[F * O];
    __shared__ float sW0[FIRST ? F * O : 1];
    __shared__ float sX[FIRST ? BN * F : 1];
    const int tid = threadIdx.x;
    for (int i = tid; i < F * O; i += NT) sW[i] = Wk[i];
    if (FIRST) {
        for (int i = tid; i < F * O; i += NT) sW0[i] = W0[i];
        int base = blockIdx.x * BN * F;
        int lim = min(BN * F, n * F - base);
        for (int i = tid; i < lim; i += NT) sX[i] = h[base + i];
    }
    const int sl = tid / NTH;
    const int t2 = tid - sl * NTH;
    const int nl = t2 / QF, q = t2 - nl * QF;
    const int node = blockIdx.x * BN + nl;
    float4 p = {0.f, 0.f, 0.f, 0.f};
    if (node < n) {
        const float4* __restrict__ h4 = (const float4*)h;
        int e0 = rowstart[node], e1 = rowstart[node + 1];
        if (ES > 1) {
            int len = e1 - e0, half = (len + 1) >> 1;
            if (sl == 0) e1 = e0 + half; else e0 += half;
        }
        int e = e0;
        for (; e + 3 < e1; e += 4) {
            int2 ea = csr[e];
            int2 eb = csr[e + 1];
            int2 ec = csr[e + 2];
            int2 ed = csr[e + 3];
            float4 ha = h4[ea.x * QF + q];
            float4 hb = h4[eb.x * QF + q];
            float4 hc = h4[ec.x * QF + q];
            float4 hd = h4[ed.x * QF + q];
            float wa = __int_as_float(ea.y), wb = __int_as_float(eb.y);
            float wc = __int_as_float(ec.y), wd = __int_as_float(ed.y);
            p.x = fmaf(wa, ha.x, p.x); p.y = fmaf(wa, ha.y, p.y);
            p.z = fmaf(wa, ha.z, p.z); p.w = fmaf(wa, ha.w, p.w);
            p.x = fmaf(wb, hb.x, p.x); p.y = fmaf(wb, hb.y, p.y);
            p.z = fmaf(wb, hb.z, p.z); p.w = fmaf(wb, hb.w, p.w);
            p.x = fmaf(wc, hc.x, p.x); p.y = fmaf(wc, hc.y, p.y);
            p.z = fmaf(wc, hc.z, p.z); p.w = fmaf(wc, hc.w, p.w);
            p.x = fmaf(wd, hd.x, p.x); p.y = fmaf(wd, hd.y, p.y);
            p.z = fmaf(wd, hd.z, p.z); p.w = fmaf(wd, hd.w, p.w);
        }
        for (; e < e1; ++e) {
            int2 ew = csr[e];
            float w = __int_as_float(ew.y);
            float4 hv = h4[ew.x * QF + q];
            p.x = fmaf(w, hv.x, p.x); p.y = fmaf(w, hv.y, p.y);
            p.z = fmaf(w, hv.z, p.z); p.w = fmaf(w, hv.w, p.w);
        }
    }
    if (ES > 1) {
        if (sl == 1 && node < n) {
            sP[nl * F + 4 * q + 0] = p.x; sP[nl * F + 4 * q + 1] = p.y;
            sP[nl * F + 4 * q + 2] = p.z; sP[nl * F + 4 * q + 3] = p.w;
        }
        __syncthreads();
        if (sl == 0 && node < n) {
            p.x += sP[nl * F + 4 * q + 0]; p.y += sP[nl * F + 4 * q + 1];
            p.z += sP[nl * F + 4 * q + 2]; p.w += sP[nl * F + 4 * q + 3];
        }
    }
    if (sl == 0 && node < n) {
        if (!FIRST) {
            float4 tv = ((const float4*)t0)[node * QF + q];
            p.x = 2.f * p.x - tv.x; p.y = 2.f * p.y - tv.y;
            p.z = 2.f * p.z - tv.z; p.w = 2.f * p.w - tv.w;
        }
        ((float4*)tout)[node * QF + q] = p;
        sT[nl * F + 4 * q + 0] = p.x; sT[nl * F + 4 * q + 1] = p.y;
        sT[nl * F + 4 * q + 2] = p.z; sT[nl * F + 4 * q + 3] = p.w;
    }
    __syncthreads();
    for (int idx = tid; idx < BN * O; idx += NT) {
        int nl2 = idx / O, o = idx - nl2 * O;
        int gn = blockIdx.x * BN + nl2;
        if (gn >= n) break;
        float s;
        if (FIRST) {
            s = bias[o];
#pragma unroll
            for (int f = 0; f < F; ++f) s = fmaf(sX[nl2 * F + f], sW0[f * O + o], s);
        } else {
            s = 0.f;
        }
#pragma unroll
        for (int f = 0; f < F; ++f) s = fmaf(sT[nl2 * F + f], sW[f * O + o], s);
        if (FIRST) acc[gn * O + o] = s;
        else       acc[gn * O + o] += s;
    }
}

// ---------------- relu + batchnorm stats: fixed-channel register accumulation ----------------
// REQUIRES gridDim.x * blockDim.x % C == 0  (stride-preserving channel)
template<int C>
__global__ void k_colstats(const float* __restrict__ a, float* __restrict__ stats, int n) {
    __shared__ float b1[C], b2[C];
    for (int i = threadIdx.x; i < C; i += blockDim.x) { b1[i] = 0.f; b2[i] = 0.f; }
    __syncthreads();
    int t0 = blockIdx.x * blockDim.x + threadIdx.x;
    int stride = gridDim.x * blockDim.x;
    int c = t0 % C;
    float s1 = 0.f, s2 = 0.f;
    for (int t = t0; t < n * C; t += stride) {
        float v = fmaxf(a[t], 0.f);
        s1 += v; s2 = fmaf(v, v, s2);
    }
    atomicAdd(&b1[c], s1); atomicAdd(&b2[c], s2);
    __syncthreads();
    for (int i = threadIdx.x; i < C; i += blockDim.x) {
        atomicAdd(&stats[i], b1[i]); atomicAdd(&stats[C + i], b2[i]);
    }
}

template<int C>
__global__ void k_bn(const float* __restrict__ a, const float* __restrict__ stats,
                     const float* __restrict__ g, const float* __restrict__ be,
                     float* __restrict__ o, int n) {
    int t = blockIdx.x * blockDim.x + threadIdx.x;
    if (t >= n * C) return;
    int c = t % C;
    float mu = stats[c] / n;
    float var = stats[C + c] / n - mu * mu;
    float v = fmaxf(a[t], 0.f);
    o[t] = (v - mu) * rsqrtf(var + EPSV) * g[c] + be[c];
}

// ---------------- xc, score, sortable key + first top-k histogram (fused) ----------------
__global__ void k_xc_score(const float* __restrict__ x1, const float* __restrict__ Wc,
                           const float* __restrict__ bc, const float* __restrict__ pw,
                           float* __restrict__ xc, float* __restrict__ score,
                           unsigned* __restrict__ key, int* __restrict__ gh, int n) {
    int i = blockIdx.x * blockDim.x + threadIdx.x;
    if (i >= n) return;
    const float* r = &x1[i * H1];
    float a = bc[0], b = bc[1];
#pragma unroll
    for (int f = 0; f < H1; ++f) { float v = r[f]; a = fmaf(v, Wc[f * 2], a); b = fmaf(v, Wc[f * 2 + 1], b); }
    xc[i * 2] = a; xc[i * 2 + 1] = b;
    float w0 = pw[0], w1 = pw[1];
    float s = tanhf((a * w0 + b * w1) / sqrtf(w0 * w0 + w1 * w1));
    score[i] = s;
    unsigned u = __float_as_uint(s);
    unsigned k = (u & 0x80000000u) ? ~u : (u | 0x80000000u);
    key[i] = k;
    atomicAdd(&gh[k >> 16], 1);
}

__global__ void k_h16b(const unsigned* __restrict__ key, const unsigned* __restrict__ pB,
                       int* __restrict__ gh, int n) {
    unsigned B = *pB;
    int i = blockIdx.x * blockDim.x + threadIdx.x;
    if (i < n && (key[i] >> 16) == B) atomicAdd(&gh[key[i] & 0xFFFFu], 1);
}

// descending scan over 65536-bin histogram: find bin with cum-from-top crossing k.
__global__ __launch_bounds__(1024)
void k_scanhist(const int* __restrict__ hist, const int* __restrict__ kin, int kdef,
                const unsigned* __restrict__ prevBin, unsigned* __restrict__ outT,
                int* __restrict__ outRem) {
    __shared__ int cs[1024];
    __shared__ int sC, sAbove;
    const int tid = threadIdx.x;
    int k = kin ? *kin : kdef;
    int s = 0;
    int base = tid * 64;
#pragma unroll 8
    for (int j = 0; j < 64; ++j) s += hist[base + j];
    cs[tid] = s;
    __syncthreads();
    int rsum = cs[1023 - tid];
    int tot; int ex = block_scan_excl_1024(rsum, tot);
    int c = 1023 - tid;
    if (ex < k && ex + cs[c] >= k) { sC = c; sAbove = ex; }
    __syncthreads();
    if (tid < 64) {
        int bin = sC * 64 + 63 - tid;
        int val = hist[bin];
        int incl = val;
#pragma unroll
        for (int off = 1; off < 64; off <<= 1) {
            int t2 = __shfl_up(incl, off, 64);
            if (tid >= off) incl += t2;
        }
        int above2 = sAbove + (incl - val);
        if (above2 < k && above2 + val >= k) {
            if (prevBin) *outT = ((*prevBin) << 16) | (unsigned)bin;
            else         *outT = (unsigned)bin;
            *outRem = k - above2;
        }
    }
}

// ---------------- parallel select (ascending-index order, eq-quota r) ----------------
__global__ __launch_bounds__(1024)
void k_selcnt(const unsigned* __restrict__ key, const unsigned* __restrict__ pT,
              int* __restrict__ bgt, int* __restrict__ beq, int n) {
    __shared__ int sgt, seq;
    if (threadIdx.x == 0) { sgt = 0; seq = 0; }
    __syncthreads();
    unsigned T = *pT;
    int i = blockIdx.x * 1024 + threadIdx.x;
    if (i < n) {
        unsigned kk = key[i];
        if (kk > T) atomicAdd(&sgt, 1);
        else if (kk == T) atomicAdd(&seq, 1);
    }
    __syncthreads();
    if (threadIdx.x == 0) { bgt[blockIdx.x] = sgt; beq[blockIdx.x] = seq; }
}

__global__ void k_seloff(const int* __restrict__ bgt, const int* __restrict__ beq,
                         const int* __restrict__ pR, int* __restrict__ eqoff,
                         int* __restrict__ soff, int nblk) {
    int t = threadIdx.x;
    int g = (t < nblk) ? bgt[t] : 0;
    int q = (t < nblk) ? beq[t] : 0;
    int gi = g, qi = q;
#pragma unroll
    for (int off = 1; off < 64; off <<= 1) {
        int a = __shfl_up(gi, off, 64);
        int b = __shfl_up(qi, off, 64);
        if (t >= off) { gi += a; qi += b; }
    }
    int qex = qi - q;
    int r = *pR;
    int eqsel = min(max(r - qex, 0), q);
    int scnt = g + eqsel;
    int si = scnt;
#pragma unroll
    for (int off = 1; off < 64; off <<= 1) {
        int a = __shfl_up(si, off, 64);
        if (t >= off) si += a;
    }
    if (t < nblk) { eqoff[t] = qex; soff[t] = si - scnt; }
}

__global__ __launch_bounds__(1024)
void k_selfill(const unsigned* __restrict__ key, const unsigned* __restrict__ pT,
               const int* __restrict__ pR, const int* __restrict__ eqoff,
               const int* __restrict__ soff, int* __restrict__ nidx,
               int* __restrict__ sel, int n) {
    unsigned T = *pT; int r = *pR;
    int b = blockIdx.x;
    int i = b * 1024 + threadIdx.x;
    unsigned kk = (i < n) ? key[i] : 0u;
    int eq = (i < n && kk == T) ? 1 : 0;
    int gt = (i < n && kk > T) ? 1 : 0;
    int eq_tot; int eq_ex = block_scan_excl_1024(eq, eq_tot);
    int sf = gt | (eq & (((eqoff[b] + eq_ex) < r) ? 1 : 0));
    int s_tot; int s_ex = block_scan_excl_1024(sf, s_tot);
    if (i < n) {
        if (sf) { int slot = soff[b] + s_ex; nidx[i] = slot; sel[slot] = i; }
        else nidx[i] = -1;
    }
}

// ---------------- pooled build: one wave per pooled row ----------------
__global__ void k_plen(const int* __restrict__ m_rowstart, const int2* __restrict__ m_csr,
                       const int* __restrict__ nidx, const int* __restrict__ sel,
                       int* __restrict__ pcnt, int* __restrict__ lens) {
    int wid = (blockIdx.x * blockDim.x + threadIdx.x) >> 6;
    int lane = threadIdx.x & 63;
    if (wid >= KSEL) return;
    int node = sel[wid];
    int e0 = m_rowstart[node], e1 = m_rowstart[node + 1];
    int cnt = 0;
    for (int e = e0 + lane; e < e1; e += 64) {
        int vs = nidx[m_csr[e].x];
        if (vs >= 0) { ++cnt; atomicAdd(&pcnt[vs], 1); }
    }
#pragma unroll
    for (int off = 32; off; off >>= 1) cnt += __shfl_down(cnt, off, 64);
    if (lane == 0) lens[wid] = cnt;
}

__global__ void k_pfill(const int* __restrict__ m_rowstart, const int2* __restrict__ m_csr,
                        const int* __restrict__ nidx, const int* __restrict__ sel,
                        const float* __restrict__ dinvp, const int* __restrict__ prs,
                        int2* __restrict__ gcsr) {
    int wid = (blockIdx.x * blockDim.x + threadIdx.x) >> 6;
    int lane = threadIdx.x & 63;
    if (wid >= KSEL) return;
    int node = sel[wid];
    int e0 = m_rowstart[node], e1 = m_rowstart[node + 1];
    float dd = dinvp[wid];
    int pos = prs[wid];
    for (int base = e0; base < e1; base += 64) {
        int e = base + lane;
        int vs = -1;
        if (e < e1) vs = nidx[m_csr[e].x];
        bool valid = vs >= 0;
        unsigned long long mask = __ballot(valid);
        if (valid) {
            int myoff = __popcll(mask & ((1ull << lane) - 1ull));
            float w = -dinvp[vs] * dd;
            gcsr[pos + myoff] = make_int2(vs, __float_as_int(w));
        }
        pos += __popcll(mask);
    }
}

// ---------------- pooled 7-hop Chebyshev, LDS-resident (single block) ----------------
__global__ __launch_bounds__(1024)
void k_pooled4(const int* __restrict__ prs_g, const int2* __restrict__ gcsr,
               const int* __restrict__ sel, const float* __restrict__ xc,
               const float* __restrict__ score, const float* __restrict__ x,
               const float* __restrict__ Wp, const float* __restrict__ bp,
               float* __restrict__ pacc_out, float* __restrict__ selpos) {
    __shared__ float bufA[2 * KSEL];         // 24 KB
    __shared__ float bufB[2 * KSEL];         // 24 KB
    __shared__ int   prs[KSEL + 1];          // 12 KB
    const int tid = threadIdx.x, NT = 1024;

    for (int j = tid; j <= KSEL; j += NT) prs[j] = prs_g[j];

    const float bp0 = bp[0], bp1 = bp[1];
    float accA[3], accB[3];
#pragma unroll
    for (int r = 0; r < 3; ++r) {
        int j = tid + r * NT;
        accA[r] = 0.f; accB[r] = 0.f;
        if (j < KSEL) {
            int i = sel[j];
            float s = score[i];
            float a = xc[2 * i] * s, b = xc[2 * i + 1] * s;
            bufA[2 * j] = a; bufA[2 * j + 1] = b;
            accA[r] = bp0 + a * Wp[0] + b * Wp[2];
            accB[r] = bp1 + a * Wp[1] + b * Wp[3];
            selpos[2 * j] = x[i * FIN + 14];
            selpos[2 * j + 1] = x[i * FIN + 15];
        }
    }
    __syncthreads();

    for (int k = 1; k < KHOP; ++k) {
        float* rb = (k & 1) ? bufA : bufB;
        float* wb = (k & 1) ? bufB : bufA;
        float w0 = Wp[k * 4 + 0], w1 = Wp[k * 4 + 1];
        float w2 = Wp[k * 4 + 2], w3 = Wp[k * 4 + 3];
#pragma unroll
        for (int r = 0; r < 3; ++r) {
            int j = tid + r * NT;
            if (j < KSEL) {
                float pa = 0.f, pb = 0.f;
                int e0 = prs[j], e1 = prs[j + 1];
                for (int e = e0; e < e1; ++e) {
                    int2 ew = gcsr[e];
                    float w = __int_as_float(ew.y);
                    pa = fmaf(w, rb[2 * ew.x], pa);
                    pb = fmaf(w, rb[2 * ew.x + 1], pb);
                }
                if (k >= 2) {
                    pa = 2.f * pa - wb[2 * j];
                    pb = 2.f * pb - wb[2 * j + 1];
                }
                wb[2 * j] = pa; wb[2 * j + 1] = pb;
                accA[r] = fmaf(pa, w0, fmaf(pb, w2, accA[r]));
                accB[r] = fmaf(pa, w1, fmaf(pb, w3, accB[r]));
            }
        }
        __syncthreads();
    }

#pragma unroll
    for (int r = 0; r < 3; ++r) {
        int j = tid + r * NT;
        if (j < KSEL) {
            pacc_out[2 * j] = accA[r];
            pacc_out[2 * j + 1] = accB[r];
        }
    }
}

// ---------------- nearest pooled node: chunked partial argmin via packed u64 ----------------
__global__ void k_near_part(const float* __restrict__ x, const float* __restrict__ selpos,
                            unsigned long long* __restrict__ best, int n) {
    __shared__ float2 sp[CHUNK];
    const int j0 = blockIdx.y * CHUNK;
    for (int j = threadIdx.x; j < CHUNK; j += blockDim.x)
        sp[j] = ((const float2*)selpos)[j0 + j];
    __syncthreads();
    int i = blockIdx.x * blockDim.x + threadIdx.x;
    if (i >= n) return;
    float px = x[i * FIN + 14], py = x[i * FIN + 15];
    float bd = 3.4e38f; int bj = 0;
#pragma unroll 2
    for (int j = 0; j < CHUNK; ++j) {
        float dx = px - sp[j].x, dy = py - sp[j].y;
        float d = fmaf(dx, dx, dy * dy);
        if (d < bd) { bd = d; bj = j0 + j; }
    }
    unsigned long long pk = ((unsigned long long)__float_as_uint(bd) << 32) | (unsigned)bj;
    atomicMin(&best[i], pk);
}

// ---------------- final linear (74 -> 10) ----------------
__global__ void k_final(const float* __restrict__ x1, const float* __restrict__ x2,
                        const float* __restrict__ xp2, const unsigned long long* __restrict__ best,
                        const float* __restrict__ W3, const float* __restrict__ b3,
                        float* __restrict__ o, int n) {
    __shared__ float sW[740], sb[10];
    for (int i = threadIdx.x; i < 740; i += blockDim.x) sW[i] = W3[i];
    if (threadIdx.x < 10) sb[threadIdx.x] = b3[threadIdx.x];
    __syncthreads();
    int t = blockIdx.x * blockDim.x + threadIdx.x;
    if (t >= n * 10) return;
    int i = t / 10, c = t - 10 * (t / 10);
    float s = sb[c];
    const float* r1 = &x1[i * H1];
#pragma unroll
    for (int f = 0; f < H1; ++f) s = fmaf(r1[f], sW[f * 10 + c], s);
    const float* r2 = &x2[i * H2];
#pragma unroll
    for (int f = 0; f < H2; ++f) s = fmaf(r2[f], sW[(H1 + f) * 10 + c], s);
    int m = (int)(best[i] & 0xFFFFFFFFull);
    s = fmaf(xp2[m * 2],     sW[720 + c], s);
    s = fmaf(xp2[m * 2 + 1], sW[730 + c], s);
    o[t] = s;
}

// =====================================================================
extern "C" void kernel_launch(void* const* d_in, const int* in_sizes, int n_in,
                              void* d_out, int out_size, void* d_ws, size_t ws_size,
                              hipStream_t stream) {
    const float* x   = (const float*)d_in[0];
    const int*   ei  = (const int*)d_in[1];
    const int*   src = ei;
    const int*   dst = ei + NE;
    const float* W1  = (const float*)d_in[2];
    const float* b1  = (const float*)d_in[3];
    const float* W2  = (const float*)d_in[4];
    const float* b2  = (const float*)d_in[5];
    const float* g1  = (const float*)d_in[6];
    const float* be1 = (const float*)d_in[7];
    const float* g2  = (const float*)d_in[8];
    const float* be2 = (const float*)d_in[9];
    const float* Wc  = (const float*)d_in[10];
    const float* bc  = (const float*)d_in[11];
    const float* pw  = (const float*)d_in[12];
    const float* Wp  = (const float*)d_in[13];
    const float* bp  = (const float*)d_in[14];
    const float* W3  = (const float*)d_in[15];
    const float* b3  = (const float*)d_in[16];
    float* out = (float*)d_out;

    // ---- workspace layout ----
    char* w = (char*)d_ws;
    auto alloc = [&](size_t bytes) -> void* {
        void* p = (void*)w;
        w += (bytes + 255) & ~(size_t)255;
        return p;
    };
    int*   cnt_dst  = (int*)alloc(NN * 4);
    float* dinv     = (float*)alloc(NN * 4);
    int*   rowstart = (int*)alloc((NN + 1) * 4);
    int*   rank     = (int*)alloc((size_t)NE * 4);
    int2*  csr      = (int2*)alloc((size_t)NE * 8);
    float* B1    = (float*)alloc((size_t)NN * H1 * 4);
    float* B2    = (float*)alloc((size_t)NN * H1 * 4);
    float* B3    = (float*)alloc((size_t)NN * H1 * 4);
    float* acc   = (float*)alloc((size_t)NN * H1 * 4);
    float* x1    = (float*)alloc((size_t)NN * H1 * 4);
    float* x2    = (float*)alloc((size_t)NN * H2 * 4);
    float* xc    = (float*)alloc((size_t)NN * 2 * 4);
    float* score = (float*)alloc(NN * 4);
    float* stats = (float*)alloc(144 * 4);   // stats1 = +0, stats2 = +72 (zeroed in k_red)
    unsigned* key   = (unsigned*)alloc(NN * 4);
    int* nidx       = (int*)alloc(NN * 4);
    int* sel        = (int*)alloc(KSEL * 4);
    unsigned long long* best = (unsigned long long*)alloc(NN * 8);
    unsigned* Tptr  = (unsigned*)alloc(4);
    int* Rptr       = (int*)alloc(4);
    unsigned* BinPtr = (unsigned*)alloc(4);
    int* RemPtr     = (int*)alloc(4);
    int* gh         = (int*)alloc(2 * 65536 * 4);   // adjacent to pcnt (one memset)
    int* pcnt       = (int*)alloc(KSEL * 4);
    int* bgt        = (int*)alloc(64 * 4);
    int* beq        = (int*)alloc(64 * 4);
    int* eqoff      = (int*)alloc(64 * 4);
    int* soff       = (int*)alloc(64 * 4);
    int* lens       = (int*)alloc(KSEL * 4);
    int* prs        = (int*)alloc((KSEL + 1) * 4);
    float* dinvp    = (float*)alloc(KSEL * 4);
    int2* gcsr      = (int2*)alloc((size_t)PCAP * 8);
    float* pacc     = (float*)alloc(KSEL * 2 * 4);
    float* selpos   = (float*)alloc(KSEL * 2 * 4);

    float* stats1 = stats;
    float* stats2 = stats + 72;

    // partials overlay B1..B2 (7.68 MB < 8.64 MB contiguous); fully consumed
    // by k_fill3 before conv1's first k_prop_gemm writes B1.
    int* partials = (int*)B1;   // [2][NB_H][NN]

    const int NBK1 = (NN + 63) / 64;   // conv1: BN=64
    const int NBK2 = (NN + 31) / 32;   // conv2: BN=32
    const int CSB = 117;  // colstats grid: 117*256 = 29952, divisible by 36

    // ---- initial memsets (gh+pcnt adjacent -> single fill) ----
    hipMemsetAsync(gh, 0, 2 * 65536 * 4 + ((KSEL * 4 + 255) & ~255), stream);
    hipMemsetAsync(best, 0xFF, NN * 8, stream);

    // ---- degree + CSR build (LDS histograms + rank; atomic-free fill) ----
    {
        dim3 gh2(NB_H, 2);
        k_hist<<<gh2, 1024, 0, stream>>>(src, dst, partials, rank);
        k_red<<<nb(NN), TPB, 0, stream>>>(partials, dinv, cnt_dst, stats);
        k_scan<<<1, 1024, 0, stream>>>(cnt_dst, rowstart, NN);
        k_fill3<<<nb(NE), TPB, 0, stream>>>(src, dst, rank, dinv, rowstart,
                                            partials + (size_t)NB_H * NN, csr, NE);
    }

    // ---- conv1: K=8, 16 -> 36 (first hop fused with W0 GEMM + bias) ----
    {
        float* rot[3] = {B1, B2, B3};
        k_prop_gemm<FIN, H1, 64, 2, true><<<NBK1, 512, 0, stream>>>(
            rowstart, csr, x, nullptr, W1 + FIN * H1, W1, b1, B1, acc, NN);
        const float* t_prev = x; const float* t_cur = B1;
        for (int kk = 2; kk < KHOP; ++kk) {
            float* o = rot[(kk - 1) % 3];
            k_prop_gemm<FIN, H1, 64, 2, false><<<NBK1, 512, 0, stream>>>(
                rowstart, csr, t_cur, t_prev, W1 + kk * FIN * H1, nullptr, nullptr, o, acc, NN);
            t_prev = t_cur; t_cur = o;
        }
        k_colstats<H1><<<CSB, TPB, 0, stream>>>(acc, stats1, NN);
        k_bn<H1><<<nb((long long)NN * H1), TPB, 0, stream>>>(acc, stats1, g1, be1, x1, NN);
    }

    // ---- conv2: K=8, 36 -> 36 (first hop fused) ----
    {
        float* rot[3] = {B1, B2, B3};
        k_prop_gemm<H1, H2, 32, 2, true><<<NBK2, 576, 0, stream>>>(
            rowstart, csr, x1, nullptr, W2 + H1 * H2, W2, b2, B1, acc, NN);
        const float* t_prev = x1; const float* t_cur = B1;
        for (int kk = 2; kk < KHOP; ++kk) {
            float* o = rot[(kk - 1) % 3];
            k_prop_gemm<H1, H2, 32, 2, false><<<NBK2, 576, 0, stream>>>(
                rowstart, csr, t_cur, t_prev, W2 + kk * H1 * H2, nullptr, nullptr, o, acc, NN);
            t_prev = t_cur; t_cur = o;
        }
        k_colstats<H2><<<CSB, TPB, 0, stream>>>(acc, stats2, NN);
        k_bn<H2><<<nb((long long)NN * H2), TPB, 0, stream>>>(acc, stats2, g2, be2, x2, NN);
    }

    // ---- xc, score, key + first 16-bit histogram (fused) ----
    k_xc_score<<<nb(NN), TPB, 0, stream>>>(x1, Wc, bc, pw, xc, score, key, gh, NN);

    // ---- top-k threshold (parallel 2x16-bit radix) ----
    k_scanhist<<<1, 1024, 0, stream>>>(gh, nullptr, KSEL, nullptr, BinPtr, RemPtr);
    k_h16b<<<nb(NN), TPB, 0, stream>>>(key, BinPtr, gh + 65536, NN);
    k_scanhist<<<1, 1024, 0, stream>>>(gh + 65536, RemPtr, 0, BinPtr, Tptr, Rptr);

    // ---- parallel select (ascending-index order) ----
    {
        const int SB = (NN + 1023) / 1024;   // 30 blocks
        k_selcnt<<<SB, 1024, 0, stream>>>(key, Tptr, bgt, beq, NN);
        k_seloff<<<1, 64, 0, stream>>>(bgt, beq, Rptr, eqoff, soff, SB);
        k_selfill<<<SB, 1024, 0, stream>>>(key, Tptr, Rptr, eqoff, soff, nidx, sel, NN);
    }

    // ---- pooled graph build (parallel) ----
    {
        const int WPB = TPB / 64;
        const int GB = (KSEL + WPB - 1) / WPB;
        k_plen<<<GB, TPB, 0, stream>>>(rowstart, csr, nidx, sel, pcnt, lens);
        k_scan_pool<<<1, 1024, 0, stream>>>(lens, prs, pcnt, dinvp);
        k_pfill<<<GB, TPB, 0, stream>>>(rowstart, csr, nidx, sel, dinvp, prs, gcsr);
    }

    // ---- pooled 7-hop pipeline (LDS-resident) ----
    k_pooled4<<<1, 1024, 0, stream>>>(prs, gcsr, sel, xc, score, x, Wp, bp, pacc, selpos);

    // ---- nearest pooled node (chunked), final linear ----
    {
        dim3 g(nb(NN), NCHUNK);
        k_near_part<<<g, TPB, 0, stream>>>(x, selpos, best, NN);
    }
    k_final<<<nb((long long)NN * 10), TPB, 0, stream>>>(x1, x2, pacc, best, W3, b3, out, NN);
}

// Round 13
// 530.837 us; speedup vs baseline: 1.0473x; 1.0473x over previous
//
#include <hip/hip_runtime.h>
#include <cstdint>

constexpr int NN   = 30000;
constexpr int NE   = 960000;
constexpr int FIN  = 16;
constexpr int H1   = 36;
constexpr int H2   = 36;
constexpr int KHOP = 8;
constexpr int KSEL = 3000;   // ceil(0.1 * 30000)
constexpr int PCAP = 32768;  // pooled-edge capacity (expected ~9600)
constexpr int NCHUNK = 12;   // candidate chunks for nearest (3000/12 = 250)
constexpr int CHUNK = KSEL / NCHUNK;
constexpr int NB_H = 32;     // histogram blocks
constexpr int EPB  = (NE + NB_H - 1) / NB_H;   // edges per histogram block (30000)
constexpr float EPSV = 1e-5f;

#define TPB 256

static inline int nb(long long t) { return (int)((t + TPB - 1) / TPB); }

// ---------------- LDS histogram: partials[y][b][j]; dst pass also records rank ----------------
__global__ __launch_bounds__(1024)
void k_hist(const int* __restrict__ src, const int* __restrict__ dst,
            int* __restrict__ partials, int* __restrict__ rank) {
    __shared__ int hist[NN];   // 120 KB
    for (int j = threadIdx.x; j < NN; j += 1024) hist[j] = 0;
    __syncthreads();
    int b = blockIdx.x;
    int e0 = b * EPB, e1 = min(NE, e0 + EPB);
    if (blockIdx.y == 0) {
        for (int e = e0 + (int)threadIdx.x; e < e1; e += 1024)
            atomicAdd(&hist[src[e]], 1);
    } else {
        for (int e = e0 + (int)threadIdx.x; e < e1; e += 1024)
            rank[e] = atomicAdd(&hist[dst[e]], 1);
    }
    __syncthreads();
    int* P = partials + ((size_t)blockIdx.y * NB_H + b) * NN;
    for (int j = threadIdx.x; j < NN; j += 1024) P[j] = hist[j];
}

// ---------------- reduce partials: dinv (src), per-block exclusive offsets + cnt_dst
//                   also zeroes the BN-stats buffer (144 floats) ----------------
__global__ void k_red(int* __restrict__ partials, float* __restrict__ dinv,
                      int* __restrict__ cnt_dst, float* __restrict__ stats) {
    if (blockIdx.x == 0 && threadIdx.x < 144) stats[threadIdx.x] = 0.f;
    int j = blockIdx.x * blockDim.x + threadIdx.x;
    if (j >= NN) return;
    const int* Ps = partials;
    int s = 0;
#pragma unroll
    for (int b = 0; b < NB_H; ++b) s += Ps[(size_t)b * NN + j];
    dinv[j] = s > 0 ? rsqrtf((float)s) : 0.0f;
    int* Pd = partials + (size_t)NB_H * NN;
    int run = 0;
#pragma unroll
    for (int b = 0; b < NB_H; ++b) {
        int t = Pd[(size_t)b * NN + j];
        Pd[(size_t)b * NN + j] = run;
        run += t;
    }
    cnt_dst[j] = run;
}

// ---------------- block scan helper (blockDim must be 1024) ----------------
__device__ __forceinline__ int block_scan_excl_1024(int val, int& total) {
    __shared__ int wsum[16];
    int tid = threadIdx.x, lane = tid & 63, wv = tid >> 6;
    int v = val;
#pragma unroll
    for (int off = 1; off < 64; off <<= 1) {
        int t = __shfl_up(v, off, 64);
        if (lane >= off) v += t;
    }
    __syncthreads();
    if (lane == 63) wsum[wv] = v;
    __syncthreads();
    if (tid < 16) {
        int w = wsum[tid];
#pragma unroll
        for (int off = 1; off < 16; off <<= 1) {
            int t = __shfl_up(w, off, 64);
            if (tid >= off) w += t;
        }
        wsum[tid] = w;
    }
    __syncthreads();
    int base = (wv > 0) ? wsum[wv - 1] : 0;
    total = wsum[15];
    return base + v - val;
}

__global__ void k_scan(const int* __restrict__ cnt, int* __restrict__ rowstart, int n) {
    __shared__ int run;
    if (threadIdx.x == 0) run = 0;
    __syncthreads();
    for (int base = 0; base < n; base += 1024) {
        int i = base + threadIdx.x;
        int v = (i < n) ? cnt[i] : 0;
        int tot; int ex = block_scan_excl_1024(v, tot);
        int r = run;
        if (i < n) rowstart[i] = r + ex;
        __syncthreads();
        if (threadIdx.x == 0) run += tot;
        __syncthreads();
    }
    if (threadIdx.x == 0) rowstart[n] = run;
}

// scan for pooled lens (n = KSEL) + fused pooled dinv from pcnt
__global__ __launch_bounds__(1024)
void k_scan_pool(const int* __restrict__ lens, int* __restrict__ prs,
                 const int* __restrict__ pcnt, float* __restrict__ dinvp) {
    __shared__ int run;
    if (threadIdx.x == 0) run = 0;
    __syncthreads();
    for (int base = 0; base < KSEL; base += 1024) {
        int i = base + threadIdx.x;
        int v = (i < KSEL) ? lens[i] : 0;
        int tot; int ex = block_scan_excl_1024(v, tot);
        int r = run;
        if (i < KSEL) prs[i] = r + ex;
        __syncthreads();
        if (threadIdx.x == 0) run += tot;
        __syncthreads();
    }
    if (threadIdx.x == 0) prs[KSEL] = run;
    for (int j = threadIdx.x; j < KSEL; j += 1024) {
        int c = pcnt[j];
        dinvp[j] = c > 0 ? rsqrtf((float)c) : 0.0f;
    }
}

// ---------------- CSR fill: pure function of precomputed rank (no atomics, no LDS) ----------------
__global__ void k_fill3(const int* __restrict__ src, const int* __restrict__ dst,
                        const int* __restrict__ rank, const float* __restrict__ dinv,
                        const int* __restrict__ rowstart, const int* __restrict__ Pd_excl,
                        int2* __restrict__ csr, int E) {
    int e = blockIdx.x * blockDim.x + threadIdx.x;
    if (e >= E) return;
    int s = src[e], d = dst[e];
    int b = e / EPB;
    int pos = rowstart[d] + Pd_excl[(size_t)b * NN + d] + rank[e];
    float w = -dinv[s] * dinv[d];
    csr[pos] = make_int2(s, __float_as_int(w));
}

// ---------------- fused prop+GEMM (R10 structure), optional first-hop W0 fusion ----------------
// FIRST: t1 = A^ h ; acc = bias + h@W0 + t1@Wk   (t0 unused)
// else : t_k = 2*A^ h - t0 ; acc += t_k@Wk
template<int F, int O, int BN, bool FIRST>
__global__ __launch_bounds__(BN * F / 4)
void k_prop_gemm(const int* __restrict__ rowstart, const int2* __restrict__ csr,
                 const float* __restrict__ h, const float* __restrict__ t0,
                 const float* __restrict__ Wk, const float* __restrict__ W0,
                 const float* __restrict__ bias, float* __restrict__ tout,
                 float* __restrict__ acc, int n) {
    constexpr int QF = F / 4;
    constexpr int NT = BN * QF;
    __shared__ float sT[BN * F];
    __shared__ float sW[F * O];
    __shared__ float sW0[FIRST ? F * O : 1];
    __shared__ float sX[FIRST ? BN * F : 1];
    const int tid = threadIdx.x;
    for (int i = tid; i < F * O; i += NT) sW[i] = Wk[i];
    if (FIRST) {
        for (int i = tid; i < F * O; i += NT) sW0[i] = W0[i];
        int base = blockIdx.x * BN * F;
        int lim = min(BN * F, n * F - base);
        for (int i = tid; i < lim; i += NT) sX[i] = h[base + i];
    }
    const int nl = tid / QF, q = tid - nl * QF;
    const int node = blockIdx.x * BN + nl;
    if (node < n) {
        const float4* __restrict__ h4 = (const float4*)h;
        float4 p = {0.f, 0.f, 0.f, 0.f};
        int e0 = rowstart[node], e1 = rowstart[node + 1];
        int e = e0;
        for (; e + 3 < e1; e += 4) {
            int2 ea = csr[e];
            int2 eb = csr[e + 1];
            int2 ec = csr[e + 2];
            int2 ed = csr[e + 3];
            float4 ha = h4[ea.x * QF + q];
            float4 hb = h4[eb.x * QF + q];
            float4 hc = h4[ec.x * QF + q];
            float4 hd = h4[ed.x * QF + q];
            float wa = __int_as_float(ea.y), wb = __int_as_float(eb.y);
            float wc = __int_as_float(ec.y), wd = __int_as_float(ed.y);
            p.x = fmaf(wa, ha.x, p.x); p.y = fmaf(wa, ha.y, p.y);
            p.z = fmaf(wa, ha.z, p.z); p.w = fmaf(wa, ha.w, p.w);
            p.x = fmaf(wb, hb.x, p.x); p.y = fmaf(wb, hb.y, p.y);
            p.z = fmaf(wb, hb.z, p.z); p.w = fmaf(wb, hb.w, p.w);
            p.x = fmaf(wc, hc.x, p.x); p.y = fmaf(wc, hc.y, p.y);
            p.z = fmaf(wc, hc.z, p.z); p.w = fmaf(wc, hc.w, p.w);
            p.x = fmaf(wd, hd.x, p.x); p.y = fmaf(wd, hd.y, p.y);
            p.z = fmaf(wd, hd.z, p.z); p.w = fmaf(wd, hd.w, p.w);
        }
        for (; e < e1; ++e) {
            int2 ew = csr[e];
            float w = __int_as_float(ew.y);
            float4 hv = h4[ew.x * QF + q];
            p.x = fmaf(w, hv.x, p.x); p.y = fmaf(w, hv.y, p.y);
            p.z = fmaf(w, hv.z, p.z); p.w = fmaf(w, hv.w, p.w);
        }
        if (!FIRST) {
            float4 tv = ((const float4*)t0)[node * QF + q];
            p.x = 2.f * p.x - tv.x; p.y = 2.f * p.y - tv.y;
            p.z = 2.f * p.z - tv.z; p.w = 2.f * p.w - tv.w;
        }
        ((float4*)tout)[node * QF + q] = p;
        sT[nl * F + 4 * q + 0] = p.x; sT[nl * F + 4 * q + 1] = p.y;
        sT[nl * F + 4 * q + 2] = p.z; sT[nl * F + 4 * q + 3] = p.w;
    }
    __syncthreads();
    for (int idx = tid; idx < BN * O; idx += NT) {
        int nl2 = idx / O, o = idx - nl2 * O;
        int gn = blockIdx.x * BN + nl2;
        if (gn >= n) break;
        float s;
        if (FIRST) {
            s = bias[o];
#pragma unroll
            for (int f = 0; f < F; ++f) s = fmaf(sX[nl2 * F + f], sW0[f * O + o], s);
        } else {
            s = 0.f;
        }
#pragma unroll
        for (int f = 0; f < F; ++f) s = fmaf(sT[nl2 * F + f], sW[f * O + o], s);
        if (FIRST) acc[gn * O + o] = s;
        else       acc[gn * O + o] += s;
    }
}

// ---------------- relu + batchnorm stats: fixed-channel register accumulation ----------------
// REQUIRES gridDim.x * blockDim.x % C == 0  (stride-preserving channel)
template<int C>
__global__ void k_colstats(const float* __restrict__ a, float* __restrict__ stats, int n) {
    __shared__ float b1[C], b2[C];
    for (int i = threadIdx.x; i < C; i += blockDim.x) { b1[i] = 0.f; b2[i] = 0.f; }
    __syncthreads();
    int t0 = blockIdx.x * blockDim.x + threadIdx.x;
    int stride = gridDim.x * blockDim.x;
    int c = t0 % C;
    float s1 = 0.f, s2 = 0.f;
    for (int t = t0; t < n * C; t += stride) {
        float v = fmaxf(a[t], 0.f);
        s1 += v; s2 = fmaf(v, v, s2);
    }
    atomicAdd(&b1[c], s1); atomicAdd(&b2[c], s2);
    __syncthreads();
    for (int i = threadIdx.x; i < C; i += blockDim.x) {
        atomicAdd(&stats[i], b1[i]); atomicAdd(&stats[C + i], b2[i]);
    }
}

template<int C>
__global__ void k_bn(const float* __restrict__ a, const float* __restrict__ stats,
                     const float* __restrict__ g, const float* __restrict__ be,
                     float* __restrict__ o, int n) {
    int t = blockIdx.x * blockDim.x + threadIdx.x;
    if (t >= n * C) return;
    int c = t % C;
    float mu = stats[c] / n;
    float var = stats[C + c] / n - mu * mu;
    float v = fmaxf(a[t], 0.f);
    o[t] = (v - mu) * rsqrtf(var + EPSV) * g[c] + be[c];
}

// ---------------- xc, score, sortable key + first top-k histogram (fused) ----------------
__global__ void k_xc_score(const float* __restrict__ x1, const float* __restrict__ Wc,
                           const float* __restrict__ bc, const float* __restrict__ pw,
                           float* __restrict__ xc, float* __restrict__ score,
                           unsigned* __restrict__ key, int* __restrict__ gh, int n) {
    int i = blockIdx.x * blockDim.x + threadIdx.x;
    if (i >= n) return;
    const float* r = &x1[i * H1];
    float a = bc[0], b = bc[1];
#pragma unroll
    for (int f = 0; f < H1; ++f) { float v = r[f]; a = fmaf(v, Wc[f * 2], a); b = fmaf(v, Wc[f * 2 + 1], b); }
    xc[i * 2] = a; xc[i * 2 + 1] = b;
    float w0 = pw[0], w1 = pw[1];
    float s = tanhf((a * w0 + b * w1) / sqrtf(w0 * w0 + w1 * w1));
    score[i] = s;
    unsigned u = __float_as_uint(s);
    unsigned k = (u & 0x80000000u) ? ~u : (u | 0x80000000u);
    key[i] = k;
    atomicAdd(&gh[k >> 16], 1);
}

__global__ void k_h16b(const unsigned* __restrict__ key, const unsigned* __restrict__ pB,
                       int* __restrict__ gh, int n) {
    unsigned B = *pB;
    int i = blockIdx.x * blockDim.x + threadIdx.x;
    if (i < n && (key[i] >> 16) == B) atomicAdd(&gh[key[i] & 0xFFFFu], 1);
}

// descending scan over 65536-bin histogram: find bin with cum-from-top crossing k.
__global__ __launch_bounds__(1024)
void k_scanhist(const int* __restrict__ hist, const int* __restrict__ kin, int kdef,
                const unsigned* __restrict__ prevBin, unsigned* __restrict__ outT,
                int* __restrict__ outRem) {
    __shared__ int cs[1024];
    __shared__ int sC, sAbove;
    const int tid = threadIdx.x;
    int k = kin ? *kin : kdef;
    int s = 0;
    int base = tid * 64;
#pragma unroll 8
    for (int j = 0; j < 64; ++j) s += hist[base + j];
    cs[tid] = s;
    __syncthreads();
    int rsum = cs[1023 - tid];
    int tot; int ex = block_scan_excl_1024(rsum, tot);
    int c = 1023 - tid;
    if (ex < k && ex + cs[c] >= k) { sC = c; sAbove = ex; }
    __syncthreads();
    if (tid < 64) {
        int bin = sC * 64 + 63 - tid;
        int val = hist[bin];
        int incl = val;
#pragma unroll
        for (int off = 1; off < 64; off <<= 1) {
            int t2 = __shfl_up(incl, off, 64);
            if (tid >= off) incl += t2;
        }
        int above2 = sAbove + (incl - val);
        if (above2 < k && above2 + val >= k) {
            if (prevBin) *outT = ((*prevBin) << 16) | (unsigned)bin;
            else         *outT = (unsigned)bin;
            *outRem = k - above2;
        }
    }
}

// ---------------- parallel select (ascending-index order, eq-quota r) ----------------
__global__ __launch_bounds__(1024)
void k_selcnt(const unsigned* __restrict__ key, const unsigned* __restrict__ pT,
              int* __restrict__ bgt, int* __restrict__ beq, int n) {
    __shared__ int sgt, seq;
    if (threadIdx.x == 0) { sgt = 0; seq = 0; }
    __syncthreads();
    unsigned T = *pT;
    int i = blockIdx.x * 1024 + threadIdx.x;
    if (i < n) {
        unsigned kk = key[i];
        if (kk > T) atomicAdd(&sgt, 1);
        else if (kk == T) atomicAdd(&seq, 1);
    }
    __syncthreads();
    if (threadIdx.x == 0) { bgt[blockIdx.x] = sgt; beq[blockIdx.x] = seq; }
}

__global__ void k_seloff(const int* __restrict__ bgt, const int* __restrict__ beq,
                         const int* __restrict__ pR, int* __restrict__ eqoff,
                         int* __restrict__ soff, int nblk) {
    int t = threadIdx.x;
    int g = (t < nblk) ? bgt[t] : 0;
    int q = (t < nblk) ? beq[t] : 0;
    int gi = g, qi = q;
#pragma unroll
    for (int off = 1; off < 64; off <<= 1) {
        int a = __shfl_up(gi, off, 64);
        int b = __shfl_up(qi, off, 64);
        if (t >= off) { gi += a; qi += b; }
    }
    int qex = qi - q;
    int r = *pR;
    int eqsel = min(max(r - qex, 0), q);
    int scnt = g + eqsel;
    int si = scnt;
#pragma unroll
    for (int off = 1; off < 64; off <<= 1) {
        int a = __shfl_up(si, off, 64);
        if (t >= off) si += a;
    }
    if (t < nblk) { eqoff[t] = qex; soff[t] = si - scnt; }
}

__global__ __launch_bounds__(1024)
void k_selfill(const unsigned* __restrict__ key, const unsigned* __restrict__ pT,
               const int* __restrict__ pR, const int* __restrict__ eqoff,
               const int* __restrict__ soff, int* __restrict__ nidx,
               int* __restrict__ sel, int n) {
    unsigned T = *pT; int r = *pR;
    int b = blockIdx.x;
    int i = b * 1024 + threadIdx.x;
    unsigned kk = (i < n) ? key[i] : 0u;
    int eq = (i < n && kk == T) ? 1 : 0;
    int gt = (i < n && kk > T) ? 1 : 0;
    int eq_tot; int eq_ex = block_scan_excl_1024(eq, eq_tot);
    int sf = gt | (eq & (((eqoff[b] + eq_ex) < r) ? 1 : 0));
    int s_tot; int s_ex = block_scan_excl_1024(sf, s_tot);
    if (i < n) {
        if (sf) { int slot = soff[b] + s_ex; nidx[i] = slot; sel[slot] = i; }
        else nidx[i] = -1;
    }
}

// ---------------- pooled build: one wave per pooled row ----------------
__global__ void k_plen(const int* __restrict__ m_rowstart, const int2* __restrict__ m_csr,
                       const int* __restrict__ nidx, const int* __restrict__ sel,
                       int* __restrict__ pcnt, int* __restrict__ lens) {
    int wid = (blockIdx.x * blockDim.x + threadIdx.x) >> 6;
    int lane = threadIdx.x & 63;
    if (wid >= KSEL) return;
    int node = sel[wid];
    int e0 = m_rowstart[node], e1 = m_rowstart[node + 1];
    int cnt = 0;
    for (int e = e0 + lane; e < e1; e += 64) {
        int vs = nidx[m_csr[e].x];
        if (vs >= 0) { ++cnt; atomicAdd(&pcnt[vs], 1); }
    }
#pragma unroll
    for (int off = 32; off; off >>= 1) cnt += __shfl_down(cnt, off, 64);
    if (lane == 0) lens[wid] = cnt;
}

__global__ void k_pfill(const int* __restrict__ m_rowstart, const int2* __restrict__ m_csr,
                        const int* __restrict__ nidx, const int* __restrict__ sel,
                        const float* __restrict__ dinvp, const int* __restrict__ prs,
                        int2* __restrict__ gcsr) {
    int wid = (blockIdx.x * blockDim.x + threadIdx.x) >> 6;
    int lane = threadIdx.x & 63;
    if (wid >= KSEL) return;
    int node = sel[wid];
    int e0 = m_rowstart[node], e1 = m_rowstart[node + 1];
    float dd = dinvp[wid];
    int pos = prs[wid];
    for (int base = e0; base < e1; base += 64) {
        int e = base + lane;
        int vs = -1;
        if (e < e1) vs = nidx[m_csr[e].x];
        bool valid = vs >= 0;
        unsigned long long mask = __ballot(valid);
        if (valid) {
            int myoff = __popcll(mask & ((1ull << lane) - 1ull));
            float w = -dinvp[vs] * dd;
            gcsr[pos + myoff] = make_int2(vs, __float_as_int(w));
        }
        pos += __popcll(mask);
    }
}

// ---------------- pooled 7-hop Chebyshev, LDS-resident (single block) ----------------
__global__ __launch_bounds__(1024)
void k_pooled4(const int* __restrict__ prs_g, const int2* __restrict__ gcsr,
               const int* __restrict__ sel, const float* __restrict__ xc,
               const float* __restrict__ score, const float* __restrict__ x,
               const float* __restrict__ Wp, const float* __restrict__ bp,
               float* __restrict__ pacc_out, float* __restrict__ selpos) {
    __shared__ float bufA[2 * KSEL];         // 24 KB
    __shared__ float bufB[2 * KSEL];         // 24 KB
    __shared__ int   prs[KSEL + 1];          // 12 KB
    const int tid = threadIdx.x, NT = 1024;

    for (int j = tid; j <= KSEL; j += NT) prs[j] = prs_g[j];

    const float bp0 = bp[0], bp1 = bp[1];
    float accA[3], accB[3];
#pragma unroll
    for (int r = 0; r < 3; ++r) {
        int j = tid + r * NT;
        accA[r] = 0.f; accB[r] = 0.f;
        if (j < KSEL) {
            int i = sel[j];
            float s = score[i];
            float a = xc[2 * i] * s, b = xc[2 * i + 1] * s;
            bufA[2 * j] = a; bufA[2 * j + 1] = b;
            accA[r] = bp0 + a * Wp[0] + b * Wp[2];
            accB[r] = bp1 + a * Wp[1] + b * Wp[3];
            selpos[2 * j] = x[i * FIN + 14];
            selpos[2 * j + 1] = x[i * FIN + 15];
        }
    }
    __syncthreads();

    for (int k = 1; k < KHOP; ++k) {
        float* rb = (k & 1) ? bufA : bufB;
        float* wb = (k & 1) ? bufB : bufA;
        float w0 = Wp[k * 4 + 0], w1 = Wp[k * 4 + 1];
        float w2 = Wp[k * 4 + 2], w3 = Wp[k * 4 + 3];
#pragma unroll
        for (int r = 0; r < 3; ++r) {
            int j = tid + r * NT;
            if (j < KSEL) {
                float pa = 0.f, pb = 0.f;
                int e0 = prs[j], e1 = prs[j + 1];
                for (int e = e0; e < e1; ++e) {
                    int2 ew = gcsr[e];
                    float w = __int_as_float(ew.y);
                    pa = fmaf(w, rb[2 * ew.x], pa);
                    pb = fmaf(w, rb[2 * ew.x + 1], pb);
                }
                if (k >= 2) {
                    pa = 2.f * pa - wb[2 * j];
                    pb = 2.f * pb - wb[2 * j + 1];
                }
                wb[2 * j] = pa; wb[2 * j + 1] = pb;
                accA[r] = fmaf(pa, w0, fmaf(pb, w2, accA[r]));
                accB[r] = fmaf(pa, w1, fmaf(pb, w3, accB[r]));
            }
        }
        __syncthreads();
    }

#pragma unroll
    for (int r = 0; r < 3; ++r) {
        int j = tid + r * NT;
        if (j < KSEL) {
            pacc_out[2 * j] = accA[r];
            pacc_out[2 * j + 1] = accB[r];
        }
    }
}

// ---------------- nearest pooled node: chunked partial argmin via packed u64 ----------------
__global__ void k_near_part(const float* __restrict__ x, const float* __restrict__ selpos,
                            unsigned long long* __restrict__ best, int n) {
    __shared__ float2 sp[CHUNK];
    const int j0 = blockIdx.y * CHUNK;
    for (int j = threadIdx.x; j < CHUNK; j += blockDim.x)
        sp[j] = ((const float2*)selpos)[j0 + j];
    __syncthreads();
    int i = blockIdx.x * blockDim.x + threadIdx.x;
    if (i >= n) return;
    float px = x[i * FIN + 14], py = x[i * FIN + 15];
    float bd = 3.4e38f; int bj = 0;
#pragma unroll 2
    for (int j = 0; j < CHUNK; ++j) {
        float dx = px - sp[j].x, dy = py - sp[j].y;
        float d = fmaf(dx, dx, dy * dy);
        if (d < bd) { bd = d; bj = j0 + j; }
    }
    unsigned long long pk = ((unsigned long long)__float_as_uint(bd) << 32) | (unsigned)bj;
    atomicMin(&best[i], pk);
}

// ---------------- final linear (74 -> 10) ----------------
__global__ void k_final(const float* __restrict__ x1, const float* __restrict__ x2,
                        const float* __restrict__ xp2, const unsigned long long* __restrict__ best,
                        const float* __restrict__ W3, const float* __restrict__ b3,
                        float* __restrict__ o, int n) {
    __shared__ float sW[740], sb[10];
    for (int i = threadIdx.x; i < 740; i += blockDim.x) sW[i] = W3[i];
    if (threadIdx.x < 10) sb[threadIdx.x] = b3[threadIdx.x];
    __syncthreads();
    int t = blockIdx.x * blockDim.x + threadIdx.x;
    if (t >= n * 10) return;
    int i = t / 10, c = t - 10 * (t / 10);
    float s = sb[c];
    const float* r1 = &x1[i * H1];
#pragma unroll
    for (int f = 0; f < H1; ++f) s = fmaf(r1[f], sW[f * 10 + c], s);
    const float* r2 = &x2[i * H2];
#pragma unroll
    for (int f = 0; f < H2; ++f) s = fmaf(r2[f], sW[(H1 + f) * 10 + c], s);
    int m = (int)(best[i] & 0xFFFFFFFFull);
    s = fmaf(xp2[m * 2],     sW[720 + c], s);
    s = fmaf(xp2[m * 2 + 1], sW[730 + c], s);
    o[t] = s;
}

// =====================================================================
extern "C" void kernel_launch(void* const* d_in, const int* in_sizes, int n_in,
                              void* d_out, int out_size, void* d_ws, size_t ws_size,
                              hipStream_t stream) {
    const float* x   = (const float*)d_in[0];
    const int*   ei  = (const int*)d_in[1];
    const int*   src = ei;
    const int*   dst = ei + NE;
    const float* W1  = (const float*)d_in[2];
    const float* b1  = (const float*)d_in[3];
    const float* W2  = (const float*)d_in[4];
    const float* b2  = (const float*)d_in[5];
    const float* g1  = (const float*)d_in[6];
    const float* be1 = (const float*)d_in[7];
    const float* g2  = (const float*)d_in[8];
    const float* be2 = (const float*)d_in[9];
    const float* Wc  = (const float*)d_in[10];
    const float* bc  = (const float*)d_in[11];
    const float* pw  = (const float*)d_in[12];
    const float* Wp  = (const float*)d_in[13];
    const float* bp  = (const float*)d_in[14];
    const float* W3  = (const float*)d_in[15];
    const float* b3  = (const float*)d_in[16];
    float* out = (float*)d_out;

    // ---- workspace layout ----
    char* w = (char*)d_ws;
    auto alloc = [&](size_t bytes) -> void* {
        void* p = (void*)w;
        w += (bytes + 255) & ~(size_t)255;
        return p;
    };
    int*   cnt_dst  = (int*)alloc(NN * 4);
    float* dinv     = (float*)alloc(NN * 4);
    int*   rowstart = (int*)alloc((NN + 1) * 4);
    int*   rank     = (int*)alloc((size_t)NE * 4);
    int2*  csr      = (int2*)alloc((size_t)NE * 8);
    float* B1    = (float*)alloc((size_t)NN * H1 * 4);
    float* B2    = (float*)alloc((size_t)NN * H1 * 4);
    float* B3    = (float*)alloc((size_t)NN * H1 * 4);
    float* acc   = (float*)alloc((size_t)NN * H1 * 4);
    float* x1    = (float*)alloc((size_t)NN * H1 * 4);
    float* x2    = (float*)alloc((size_t)NN * H2 * 4);
    float* xc    = (float*)alloc((size_t)NN * 2 * 4);
    float* score = (float*)alloc(NN * 4);
    float* stats = (float*)alloc(144 * 4);   // stats1 = +0, stats2 = +72 (zeroed in k_red)
    unsigned* key   = (unsigned*)alloc(NN * 4);
    int* nidx       = (int*)alloc(NN * 4);
    int* sel        = (int*)alloc(KSEL * 4);
    unsigned long long* best = (unsigned long long*)alloc(NN * 8);
    unsigned* Tptr  = (unsigned*)alloc(4);
    int* Rptr       = (int*)alloc(4);
    unsigned* BinPtr = (unsigned*)alloc(4);
    int* RemPtr     = (int*)alloc(4);
    int* gh         = (int*)alloc(2 * 65536 * 4);   // adjacent to pcnt (one memset)
    int* pcnt       = (int*)alloc(KSEL * 4);
    int* bgt        = (int*)alloc(64 * 4);
    int* beq        = (int*)alloc(64 * 4);
    int* eqoff      = (int*)alloc(64 * 4);
    int* soff       = (int*)alloc(64 * 4);
    int* lens       = (int*)alloc(KSEL * 4);
    int* prs        = (int*)alloc((KSEL + 1) * 4);
    float* dinvp    = (float*)alloc(KSEL * 4);
    int2* gcsr      = (int2*)alloc((size_t)PCAP * 8);
    float* pacc     = (float*)alloc(KSEL * 2 * 4);
    float* selpos   = (float*)alloc(KSEL * 2 * 4);

    float* stats1 = stats;
    float* stats2 = stats + 72;

    // partials overlay B1..B2 (7.68 MB < 8.64 MB contiguous); fully consumed
    // by k_fill3 before conv1's first k_prop_gemm writes B1.
    int* partials = (int*)B1;   // [2][NB_H][NN]

    const int NBK = (NN + 63) / 64;
    const int CSB = 117;  // colstats grid: 117*256 = 29952, divisible by 36

    // ---- initial memsets (gh+pcnt adjacent -> single fill) ----
    hipMemsetAsync(gh, 0, 2 * 65536 * 4 + ((KSEL * 4 + 255) & ~255), stream);
    hipMemsetAsync(best, 0xFF, NN * 8, stream);

    // ---- degree + CSR build (LDS histograms + rank; atomic-free fill) ----
    {
        dim3 gh2(NB_H, 2);
        k_hist<<<gh2, 1024, 0, stream>>>(src, dst, partials, rank);
        k_red<<<nb(NN), TPB, 0, stream>>>(partials, dinv, cnt_dst, stats);
        k_scan<<<1, 1024, 0, stream>>>(cnt_dst, rowstart, NN);
        k_fill3<<<nb(NE), TPB, 0, stream>>>(src, dst, rank, dinv, rowstart,
                                            partials + (size_t)NB_H * NN, csr, NE);
    }

    // ---- conv1: K=8, 16 -> 36 (first hop fused with W0 GEMM + bias) ----
    {
        float* rot[3] = {B1, B2, B3};
        k_prop_gemm<FIN, H1, 64, true><<<NBK, 64 * (FIN / 4), 0, stream>>>(
            rowstart, csr, x, nullptr, W1 + FIN * H1, W1, b1, B1, acc, NN);
        const float* t_prev = x; const float* t_cur = B1;
        for (int kk = 2; kk < KHOP; ++kk) {
            float* o = rot[(kk - 1) % 3];
            k_prop_gemm<FIN, H1, 64, false><<<NBK, 64 * (FIN / 4), 0, stream>>>(
                rowstart, csr, t_cur, t_prev, W1 + kk * FIN * H1, nullptr, nullptr, o, acc, NN);
            t_prev = t_cur; t_cur = o;
        }
        k_colstats<H1><<<CSB, TPB, 0, stream>>>(acc, stats1, NN);
        k_bn<H1><<<nb((long long)NN * H1), TPB, 0, stream>>>(acc, stats1, g1, be1, x1, NN);
    }

    // ---- conv2: K=8, 36 -> 36 (first hop fused) ----
    {
        float* rot[3] = {B1, B2, B3};
        k_prop_gemm<H1, H2, 64, true><<<NBK, 64 * (H1 / 4), 0, stream>>>(
            rowstart, csr, x1, nullptr, W2 + H1 * H2, W2, b2, B1, acc, NN);
        const float* t_prev = x1; const float* t_cur = B1;
        for (int kk = 2; kk < KHOP; ++kk) {
            float* o = rot[(kk - 1) % 3];
            k_prop_gemm<H1, H2, 64, false><<<NBK, 64 * (H1 / 4), 0, stream>>>(
                rowstart, csr, t_cur, t_prev, W2 + kk * H1 * H2, nullptr, nullptr, o, acc, NN);
            t_prev = t_cur; t_cur = o;
        }
        k_colstats<H2><<<CSB, TPB, 0, stream>>>(acc, stats2, NN);
        k_bn<H2><<<nb((long long)NN * H2), TPB, 0, stream>>>(acc, stats2, g2, be2, x2, NN);
    }

    // ---- xc, score, key + first 16-bit histogram (fused) ----
    k_xc_score<<<nb(NN), TPB, 0, stream>>>(x1, Wc, bc, pw, xc, score, key, gh, NN);

    // ---- top-k threshold (parallel 2x16-bit radix) ----
    k_scanhist<<<1, 1024, 0, stream>>>(gh, nullptr, KSEL, nullptr, BinPtr, RemPtr);
    k_h16b<<<nb(NN), TPB, 0, stream>>>(key, BinPtr, gh + 65536, NN);
    k_scanhist<<<1, 1024, 0, stream>>>(gh + 65536, RemPtr, 0, BinPtr, Tptr, Rptr);

    // ---- parallel select (ascending-index order) ----
    {
        const int SB = (NN + 1023) / 1024;   // 30 blocks
        k_selcnt<<<SB, 1024, 0, stream>>>(key, Tptr, bgt, beq, NN);
        k_seloff<<<1, 64, 0, stream>>>(bgt, beq, Rptr, eqoff, soff, SB);
        k_selfill<<<SB, 1024, 0, stream>>>(key, Tptr, Rptr, eqoff, soff, nidx, sel, NN);
    }

    // ---- pooled graph build (parallel) ----
    {
        const int WPB = TPB / 64;
        const int GB = (KSEL + WPB - 1) / WPB;
        k_plen<<<GB, TPB, 0, stream>>>(rowstart, csr, nidx, sel, pcnt, lens);
        k_scan_pool<<<1, 1024, 0, stream>>>(lens, prs, pcnt, dinvp);
        k_pfill<<<GB, TPB, 0, stream>>>(rowstart, csr, nidx, sel, dinvp, prs, gcsr);
    }

    // ---- pooled 7-hop pipeline (LDS-resident) ----
    k_pooled4<<<1, 1024, 0, stream>>>(prs, gcsr, sel, xc, score, x, Wp, bp, pacc, selpos);

    // ---- nearest pooled node (chunked), final linear ----
    {
        dim3 g(nb(NN), NCHUNK);
        k_near_part<<<g, TPB, 0, stream>>>(x, selpos, best, NN);
    }
    k_final<<<nb((long long)NN * 10), TPB, 0, stream>>>(x1, x2, pacc, best, W3, b3, out, NN);
}

// Round 14
// 504.055 us; speedup vs baseline: 1.1030x; 1.0531x over previous
//
#include <hip/hip_runtime.h>
#include <cstdint>

constexpr int NN   = 30000;
constexpr int NE   = 960000;
constexpr int FIN  = 16;
constexpr int H1   = 36;
constexpr int H2   = 36;
constexpr int KHOP = 8;
constexpr int KSEL = 3000;   // ceil(0.1 * 30000)
constexpr int PCAP = 32768;  // pooled-edge capacity (expected ~9600)
constexpr int NCHUNK = 12;   // candidate chunks for nearest (3000/12 = 250)
constexpr int CHUNK = KSEL / NCHUNK;
constexpr int NB_H = 32;     // histogram blocks
constexpr int EPB  = (NE + NB_H - 1) / NB_H;   // edges per histogram block (30000)
constexpr float EPSV = 1e-5f;

#define TPB 256

static inline int nb(long long t) { return (int)((t + TPB - 1) / TPB); }

// ---------------- LDS histogram: partials[y][b][j]; dst pass also records rank ----------------
__global__ __launch_bounds__(1024)
void k_hist(const int* __restrict__ src, const int* __restrict__ dst,
            int* __restrict__ partials, int* __restrict__ rank) {
    __shared__ int hist[NN];   // 120 KB
    for (int j = threadIdx.x; j < NN; j += 1024) hist[j] = 0;
    __syncthreads();
    int b = blockIdx.x;
    int e0 = b * EPB, e1 = min(NE, e0 + EPB);
    if (blockIdx.y == 0) {
        for (int e = e0 + (int)threadIdx.x; e < e1; e += 1024)
            atomicAdd(&hist[src[e]], 1);
    } else {
        for (int e = e0 + (int)threadIdx.x; e < e1; e += 1024)
            rank[e] = atomicAdd(&hist[dst[e]], 1);
    }
    __syncthreads();
    int* P = partials + ((size_t)blockIdx.y * NB_H + b) * NN;
    for (int j = threadIdx.x; j < NN; j += 1024) P[j] = hist[j];
}

// ---------------- reduce partials: dinv (src), per-block exclusive offsets + cnt_dst
//                   also zeroes the BN-stats buffer (144 floats) ----------------
__global__ void k_red(int* __restrict__ partials, float* __restrict__ dinv,
                      int* __restrict__ cnt_dst, float* __restrict__ stats) {
    if (blockIdx.x == 0 && threadIdx.x < 144) stats[threadIdx.x] = 0.f;
    int j = blockIdx.x * blockDim.x + threadIdx.x;
    if (j >= NN) return;
    const int* Ps = partials;
    int s = 0;
#pragma unroll
    for (int b = 0; b < NB_H; ++b) s += Ps[(size_t)b * NN + j];
    dinv[j] = s > 0 ? rsqrtf((float)s) : 0.0f;
    int* Pd = partials + (size_t)NB_H * NN;
    int run = 0;
#pragma unroll
    for (int b = 0; b < NB_H; ++b) {
        int t = Pd[(size_t)b * NN + j];
        Pd[(size_t)b * NN + j] = run;
        run += t;
    }
    cnt_dst[j] = run;
}

// ---------------- block scan helper (blockDim must be 1024) ----------------
__device__ __forceinline__ int block_scan_excl_1024(int val, int& total) {
    __shared__ int wsum[16];
    int tid = threadIdx.x, lane = tid & 63, wv = tid >> 6;
    int v = val;
#pragma unroll
    for (int off = 1; off < 64; off <<= 1) {
        int t = __shfl_up(v, off, 64);
        if (lane >= off) v += t;
    }
    __syncthreads();
    if (lane == 63) wsum[wv] = v;
    __syncthreads();
    if (tid < 16) {
        int w = wsum[tid];
#pragma unroll
        for (int off = 1; off < 16; off <<= 1) {
            int t = __shfl_up(w, off, 64);
            if (tid >= off) w += t;
        }
        wsum[tid] = w;
    }
    __syncthreads();
    int base = (wv > 0) ? wsum[wv - 1] : 0;
    total = wsum[15];
    return base + v - val;
}

__global__ void k_scan(const int* __restrict__ cnt, int* __restrict__ rowstart, int n) {
    __shared__ int run;
    if (threadIdx.x == 0) run = 0;
    __syncthreads();
    for (int base = 0; base < n; base += 1024) {
        int i = base + threadIdx.x;
        int v = (i < n) ? cnt[i] : 0;
        int tot; int ex = block_scan_excl_1024(v, tot);
        int r = run;
        if (i < n) rowstart[i] = r + ex;
        __syncthreads();
        if (threadIdx.x == 0) run += tot;
        __syncthreads();
    }
    if (threadIdx.x == 0) rowstart[n] = run;
}

// scan for pooled lens (n = KSEL) + fused pooled dinv from pcnt
__global__ __launch_bounds__(1024)
void k_scan_pool(const int* __restrict__ lens, int* __restrict__ prs,
                 const int* __restrict__ pcnt, float* __restrict__ dinvp) {
    __shared__ int run;
    if (threadIdx.x == 0) run = 0;
    __syncthreads();
    for (int base = 0; base < KSEL; base += 1024) {
        int i = base + threadIdx.x;
        int v = (i < KSEL) ? lens[i] : 0;
        int tot; int ex = block_scan_excl_1024(v, tot);
        int r = run;
        if (i < KSEL) prs[i] = r + ex;
        __syncthreads();
        if (threadIdx.x == 0) run += tot;
        __syncthreads();
    }
    if (threadIdx.x == 0) prs[KSEL] = run;
    for (int j = threadIdx.x; j < KSEL; j += 1024) {
        int c = pcnt[j];
        dinvp[j] = c > 0 ? rsqrtf((float)c) : 0.0f;
    }
}

// ---------------- CSR fill: pure function of precomputed rank (no atomics, no LDS) ----------------
__global__ void k_fill3(const int* __restrict__ src, const int* __restrict__ dst,
                        const int* __restrict__ rank, const float* __restrict__ dinv,
                        const int* __restrict__ rowstart, const int* __restrict__ Pd_excl,
                        int2* __restrict__ csr, int E) {
    int e = blockIdx.x * blockDim.x + threadIdx.x;
    if (e >= E) return;
    int s = src[e], d = dst[e];
    int b = e / EPB;
    int pos = rowstart[d] + Pd_excl[(size_t)b * NN + d] + rank[e];
    float w = -dinv[s] * dinv[d];
    csr[pos] = make_int2(s, __float_as_int(w));
}

// ---------------- fused prop+GEMM with LDS-staged edge range, optional first-hop W0 fusion ----------------
// FIRST: t1 = A^ h ; acc = bias + h@W0 + t1@Wk   (t0 unused)
// else : t_k = 2*A^ h - t0 ; acc += t_k@Wk
// The block's rows are contiguous in the dst-grouped CSR -> stage its whole edge
// range into LDS once (coalesced, read-once) and broadcast-read in the gather loop.
#define PROP_BODY(EDGE_AT)                                                    \
    for (; e + 3 < e1; e += 4) {                                              \
        int2 ea = EDGE_AT(e);                                                 \
        int2 eb = EDGE_AT(e + 1);                                             \
        int2 ec = EDGE_AT(e + 2);                                             \
        int2 ed = EDGE_AT(e + 3);                                             \
        float4 ha = h4[ea.x * QF + q];                                        \
        float4 hb = h4[eb.x * QF + q];                                        \
        float4 hc = h4[ec.x * QF + q];                                        \
        float4 hd = h4[ed.x * QF + q];                                        \
        float wa = __int_as_float(ea.y), wb = __int_as_float(eb.y);           \
        float wc = __int_as_float(ec.y), wd = __int_as_float(ed.y);           \
        p.x = fmaf(wa, ha.x, p.x); p.y = fmaf(wa, ha.y, p.y);                 \
        p.z = fmaf(wa, ha.z, p.z); p.w = fmaf(wa, ha.w, p.w);                 \
        p.x = fmaf(wb, hb.x, p.x); p.y = fmaf(wb, hb.y, p.y);                 \
        p.z = fmaf(wb, hb.z, p.z); p.w = fmaf(wb, hb.w, p.w);                 \
        p.x = fmaf(wc, hc.x, p.x); p.y = fmaf(wc, hc.y, p.y);                 \
        p.z = fmaf(wc, hc.z, p.z); p.w = fmaf(wc, hc.w, p.w);                 \
        p.x = fmaf(wd, hd.x, p.x); p.y = fmaf(wd, hd.y, p.y);                 \
        p.z = fmaf(wd, hd.z, p.z); p.w = fmaf(wd, hd.w, p.w);                 \
    }                                                                         \
    for (; e < e1; ++e) {                                                     \
        int2 ew = EDGE_AT(e);                                                 \
        float w = __int_as_float(ew.y);                                       \
        float4 hv = h4[ew.x * QF + q];                                        \
        p.x = fmaf(w, hv.x, p.x); p.y = fmaf(w, hv.y, p.y);                   \
        p.z = fmaf(w, hv.z, p.z); p.w = fmaf(w, hv.w, p.w);                   \
    }

template<int F, int O, int BN, bool FIRST>
__global__ __launch_bounds__(BN * F / 4)
void k_prop_gemm(const int* __restrict__ rowstart, const int2* __restrict__ csr,
                 const float* __restrict__ h, const float* __restrict__ t0,
                 const float* __restrict__ Wk, const float* __restrict__ W0,
                 const float* __restrict__ bias, float* __restrict__ tout,
                 float* __restrict__ acc, int n) {
    constexpr int QF = F / 4;
    constexpr int NT = BN * QF;
    constexpr int ECAP = 2560;   // block edge-count ~Poisson(2048), sigma~45; >11 sigma margin
    __shared__ float sT[BN * F];
    __shared__ float sW[F * O];
    __shared__ float sW0[FIRST ? F * O : 1];
    __shared__ float sX[FIRST ? BN * F : 1];
    __shared__ int2  sE[ECAP];
    const int tid = threadIdx.x;
    for (int i = tid; i < F * O; i += NT) sW[i] = Wk[i];
    if (FIRST) {
        for (int i = tid; i < F * O; i += NT) sW0[i] = W0[i];
        int base = blockIdx.x * BN * F;
        int lim = min(BN * F, n * F - base);
        for (int i = tid; i < lim; i += NT) sX[i] = h[base + i];
    }
    const int rowLo = blockIdx.x * BN;
    const int rowHi = min(n, rowLo + BN);
    const int e0b = rowstart[rowLo];
    const int ecnt = rowstart[rowHi] - e0b;
    const bool staged = (ecnt <= ECAP);
    if (staged) {
        for (int i = tid; i < ecnt; i += NT) sE[i] = csr[e0b + i];
    }
    __syncthreads();
    const int nl = tid / QF, q = tid - nl * QF;
    const int node = rowLo + nl;
    if (node < n) {
        const float4* __restrict__ h4 = (const float4*)h;
        float4 p = {0.f, 0.f, 0.f, 0.f};
        int e0g = rowstart[node], e1g = rowstart[node + 1];
        if (staged) {
            int e = e0g - e0b, e1 = e1g - e0b;
#define EDGE_LDS(idx) sE[idx]
            PROP_BODY(EDGE_LDS)
#undef EDGE_LDS
        } else {
            int e = e0g, e1 = e1g;
#define EDGE_GBL(idx) csr[idx]
            PROP_BODY(EDGE_GBL)
#undef EDGE_GBL
        }
        if (!FIRST) {
            float4 tv = ((const float4*)t0)[node * QF + q];
            p.x = 2.f * p.x - tv.x; p.y = 2.f * p.y - tv.y;
            p.z = 2.f * p.z - tv.z; p.w = 2.f * p.w - tv.w;
        }
        ((float4*)tout)[node * QF + q] = p;
        sT[nl * F + 4 * q + 0] = p.x; sT[nl * F + 4 * q + 1] = p.y;
        sT[nl * F + 4 * q + 2] = p.z; sT[nl * F + 4 * q + 3] = p.w;
    }
    __syncthreads();
    for (int idx = tid; idx < BN * O; idx += NT) {
        int nl2 = idx / O, o = idx - nl2 * O;
        int gn = rowLo + nl2;
        if (gn >= n) break;
        float s;
        if (FIRST) {
            s = bias[o];
#pragma unroll
            for (int f = 0; f < F; ++f) s = fmaf(sX[nl2 * F + f], sW0[f * O + o], s);
        } else {
            s = 0.f;
        }
#pragma unroll
        for (int f = 0; f < F; ++f) s = fmaf(sT[nl2 * F + f], sW[f * O + o], s);
        if (FIRST) acc[gn * O + o] = s;
        else       acc[gn * O + o] += s;
    }
}

// ---------------- relu + batchnorm stats: fixed-channel register accumulation ----------------
// REQUIRES gridDim.x * blockDim.x % C == 0  (stride-preserving channel)
template<int C>
__global__ void k_colstats(const float* __restrict__ a, float* __restrict__ stats, int n) {
    __shared__ float b1[C], b2[C];
    for (int i = threadIdx.x; i < C; i += blockDim.x) { b1[i] = 0.f; b2[i] = 0.f; }
    __syncthreads();
    int t0 = blockIdx.x * blockDim.x + threadIdx.x;
    int stride = gridDim.x * blockDim.x;
    int c = t0 % C;
    float s1 = 0.f, s2 = 0.f;
    for (int t = t0; t < n * C; t += stride) {
        float v = fmaxf(a[t], 0.f);
        s1 += v; s2 = fmaf(v, v, s2);
    }
    atomicAdd(&b1[c], s1); atomicAdd(&b2[c], s2);
    __syncthreads();
    for (int i = threadIdx.x; i < C; i += blockDim.x) {
        atomicAdd(&stats[i], b1[i]); atomicAdd(&stats[C + i], b2[i]);
    }
}

template<int C>
__global__ void k_bn(const float* __restrict__ a, const float* __restrict__ stats,
                     const float* __restrict__ g, const float* __restrict__ be,
                     float* __restrict__ o, int n) {
    int t = blockIdx.x * blockDim.x + threadIdx.x;
    if (t >= n * C) return;
    int c = t % C;
    float mu = stats[c] / n;
    float var = stats[C + c] / n - mu * mu;
    float v = fmaxf(a[t], 0.f);
    o[t] = (v - mu) * rsqrtf(var + EPSV) * g[c] + be[c];
}

// ---------------- xc, score, sortable key + first top-k histogram (fused) ----------------
__global__ void k_xc_score(const float* __restrict__ x1, const float* __restrict__ Wc,
                           const float* __restrict__ bc, const float* __restrict__ pw,
                           float* __restrict__ xc, float* __restrict__ score,
                           unsigned* __restrict__ key, int* __restrict__ gh, int n) {
    int i = blockIdx.x * blockDim.x + threadIdx.x;
    if (i >= n) return;
    const float* r = &x1[i * H1];
    float a = bc[0], b = bc[1];
#pragma unroll
    for (int f = 0; f < H1; ++f) { float v = r[f]; a = fmaf(v, Wc[f * 2], a); b = fmaf(v, Wc[f * 2 + 1], b); }
    xc[i * 2] = a; xc[i * 2 + 1] = b;
    float w0 = pw[0], w1 = pw[1];
    float s = tanhf((a * w0 + b * w1) / sqrtf(w0 * w0 + w1 * w1));
    score[i] = s;
    unsigned u = __float_as_uint(s);
    unsigned k = (u & 0x80000000u) ? ~u : (u | 0x80000000u);
    key[i] = k;
    atomicAdd(&gh[k >> 16], 1);
}

__global__ void k_h16b(const unsigned* __restrict__ key, const unsigned* __restrict__ pB,
                       int* __restrict__ gh, int n) {
    unsigned B = *pB;
    int i = blockIdx.x * blockDim.x + threadIdx.x;
    if (i < n && (key[i] >> 16) == B) atomicAdd(&gh[key[i] & 0xFFFFu], 1);
}

// descending scan over 65536-bin histogram: find bin with cum-from-top crossing k.
__global__ __launch_bounds__(1024)
void k_scanhist(const int* __restrict__ hist, const int* __restrict__ kin, int kdef,
                const unsigned* __restrict__ prevBin, unsigned* __restrict__ outT,
                int* __restrict__ outRem) {
    __shared__ int cs[1024];
    __shared__ int sC, sAbove;
    const int tid = threadIdx.x;
    int k = kin ? *kin : kdef;
    int s = 0;
    int base = tid * 64;
#pragma unroll 8
    for (int j = 0; j < 64; ++j) s += hist[base + j];
    cs[tid] = s;
    __syncthreads();
    int rsum = cs[1023 - tid];
    int tot; int ex = block_scan_excl_1024(rsum, tot);
    int c = 1023 - tid;
    if (ex < k && ex + cs[c] >= k) { sC = c; sAbove = ex; }
    __syncthreads();
    if (tid < 64) {
        int bin = sC * 64 + 63 - tid;
        int val = hist[bin];
        int incl = val;
#pragma unroll
        for (int off = 1; off < 64; off <<= 1) {
            int t2 = __shfl_up(incl, off, 64);
            if (tid >= off) incl += t2;
        }
        int above2 = sAbove + (incl - val);
        if (above2 < k && above2 + val >= k) {
            if (prevBin) *outT = ((*prevBin) << 16) | (unsigned)bin;
            else         *outT = (unsigned)bin;
            *outRem = k - above2;
        }
    }
}

// ---------------- parallel select (ascending-index order, eq-quota r) ----------------
__global__ __launch_bounds__(1024)
void k_selcnt(const unsigned* __restrict__ key, const unsigned* __restrict__ pT,
              int* __restrict__ bgt, int* __restrict__ beq, int n) {
    __shared__ int sgt, seq;
    if (threadIdx.x == 0) { sgt = 0; seq = 0; }
    __syncthreads();
    unsigned T = *pT;
    int i = blockIdx.x * 1024 + threadIdx.x;
    if (i < n) {
        unsigned kk = key[i];
        if (kk > T) atomicAdd(&sgt, 1);
        else if (kk == T) atomicAdd(&seq, 1);
    }
    __syncthreads();
    if (threadIdx.x == 0) { bgt[blockIdx.x] = sgt; beq[blockIdx.x] = seq; }
}

__global__ void k_seloff(const int* __restrict__ bgt, const int* __restrict__ beq,
                         const int* __restrict__ pR, int* __restrict__ eqoff,
                         int* __restrict__ soff, int nblk) {
    int t = threadIdx.x;
    int g = (t < nblk) ? bgt[t] : 0;
    int q = (t < nblk) ? beq[t] : 0;
    int gi = g, qi = q;
#pragma unroll
    for (int off = 1; off < 64; off <<= 1) {
        int a = __shfl_up(gi, off, 64);
        int b = __shfl_up(qi, off, 64);
        if (t >= off) { gi += a; qi += b; }
    }
    int qex = qi - q;
    int r = *pR;
    int eqsel = min(max(r - qex, 0), q);
    int scnt = g + eqsel;
    int si = scnt;
#pragma unroll
    for (int off = 1; off < 64; off <<= 1) {
        int a = __shfl_up(si, off, 64);
        if (t >= off) si += a;
    }
    if (t < nblk) { eqoff[t] = qex; soff[t] = si - scnt; }
}

__global__ __launch_bounds__(1024)
void k_selfill(const unsigned* __restrict__ key, const unsigned* __restrict__ pT,
               const int* __restrict__ pR, const int* __restrict__ eqoff,
               const int* __restrict__ soff, int* __restrict__ nidx,
               int* __restrict__ sel, int n) {
    unsigned T = *pT; int r = *pR;
    int b = blockIdx.x;
    int i = b * 1024 + threadIdx.x;
    unsigned kk = (i < n) ? key[i] : 0u;
    int eq = (i < n && kk == T) ? 1 : 0;
    int gt = (i < n && kk > T) ? 1 : 0;
    int eq_tot; int eq_ex = block_scan_excl_1024(eq, eq_tot);
    int sf = gt | (eq & (((eqoff[b] + eq_ex) < r) ? 1 : 0));
    int s_tot; int s_ex = block_scan_excl_1024(sf, s_tot);
    if (i < n) {
        if (sf) { int slot = soff[b] + s_ex; nidx[i] = slot; sel[slot] = i; }
        else nidx[i] = -1;
    }
}

// ---------------- pooled build: one wave per pooled row ----------------
__global__ void k_plen(const int* __restrict__ m_rowstart, const int2* __restrict__ m_csr,
                       const int* __restrict__ nidx, const int* __restrict__ sel,
                       int* __restrict__ pcnt, int* __restrict__ lens) {
    int wid = (blockIdx.x * blockDim.x + threadIdx.x) >> 6;
    int lane = threadIdx.x & 63;
    if (wid >= KSEL) return;
    int node = sel[wid];
    int e0 = m_rowstart[node], e1 = m_rowstart[node + 1];
    int cnt = 0;
    for (int e = e0 + lane; e < e1; e += 64) {
        int vs = nidx[m_csr[e].x];
        if (vs >= 0) { ++cnt; atomicAdd(&pcnt[vs], 1); }
    }
#pragma unroll
    for (int off = 32; off; off >>= 1) cnt += __shfl_down(cnt, off, 64);
    if (lane == 0) lens[wid] = cnt;
}

__global__ void k_pfill(const int* __restrict__ m_rowstart, const int2* __restrict__ m_csr,
                        const int* __restrict__ nidx, const int* __restrict__ sel,
                        const float* __restrict__ dinvp, const int* __restrict__ prs,
                        int2* __restrict__ gcsr) {
    int wid = (blockIdx.x * blockDim.x + threadIdx.x) >> 6;
    int lane = threadIdx.x & 63;
    if (wid >= KSEL) return;
    int node = sel[wid];
    int e0 = m_rowstart[node], e1 = m_rowstart[node + 1];
    float dd = dinvp[wid];
    int pos = prs[wid];
    for (int base = e0; base < e1; base += 64) {
        int e = base + lane;
        int vs = -1;
        if (e < e1) vs = nidx[m_csr[e].x];
        bool valid = vs >= 0;
        unsigned long long mask = __ballot(valid);
        if (valid) {
            int myoff = __popcll(mask & ((1ull << lane) - 1ull));
            float w = -dinvp[vs] * dd;
            gcsr[pos + myoff] = make_int2(vs, __float_as_int(w));
        }
        pos += __popcll(mask);
    }
}

// ---------------- pooled 7-hop Chebyshev, LDS-resident (single block) ----------------
__global__ __launch_bounds__(1024)
void k_pooled4(const int* __restrict__ prs_g, const int2* __restrict__ gcsr,
               const int* __restrict__ sel, const float* __restrict__ xc,
               const float* __restrict__ score, const float* __restrict__ x,
               const float* __restrict__ Wp, const float* __restrict__ bp,
               float* __restrict__ pacc_out, float* __restrict__ selpos) {
    __shared__ float bufA[2 * KSEL];         // 24 KB
    __shared__ float bufB[2 * KSEL];         // 24 KB
    __shared__ int   prs[KSEL + 1];          // 12 KB
    const int tid = threadIdx.x, NT = 1024;

    for (int j = tid; j <= KSEL; j += NT) prs[j] = prs_g[j];

    const float bp0 = bp[0], bp1 = bp[1];
    float accA[3], accB[3];
#pragma unroll
    for (int r = 0; r < 3; ++r) {
        int j = tid + r * NT;
        accA[r] = 0.f; accB[r] = 0.f;
        if (j < KSEL) {
            int i = sel[j];
            float s = score[i];
            float a = xc[2 * i] * s, b = xc[2 * i + 1] * s;
            bufA[2 * j] = a; bufA[2 * j + 1] = b;
            accA[r] = bp0 + a * Wp[0] + b * Wp[2];
            accB[r] = bp1 + a * Wp[1] + b * Wp[3];
            selpos[2 * j] = x[i * FIN + 14];
            selpos[2 * j + 1] = x[i * FIN + 15];
        }
    }
    __syncthreads();

    for (int k = 1; k < KHOP; ++k) {
        float* rb = (k & 1) ? bufA : bufB;
        float* wb = (k & 1) ? bufB : bufA;
        float w0 = Wp[k * 4 + 0], w1 = Wp[k * 4 + 1];
        float w2 = Wp[k * 4 + 2], w3 = Wp[k * 4 + 3];
#pragma unroll
        for (int r = 0; r < 3; ++r) {
            int j = tid + r * NT;
            if (j < KSEL) {
                float pa = 0.f, pb = 0.f;
                int e0 = prs[j], e1 = prs[j + 1];
                for (int e = e0; e < e1; ++e) {
                    int2 ew = gcsr[e];
                    float w = __int_as_float(ew.y);
                    pa = fmaf(w, rb[2 * ew.x], pa);
                    pb = fmaf(w, rb[2 * ew.x + 1], pb);
                }
                if (k >= 2) {
                    pa = 2.f * pa - wb[2 * j];
                    pb = 2.f * pb - wb[2 * j + 1];
                }
                wb[2 * j] = pa; wb[2 * j + 1] = pb;
                accA[r] = fmaf(pa, w0, fmaf(pb, w2, accA[r]));
                accB[r] = fmaf(pa, w1, fmaf(pb, w3, accB[r]));
            }
        }
        __syncthreads();
    }

#pragma unroll
    for (int r = 0; r < 3; ++r) {
        int j = tid + r * NT;
        if (j < KSEL) {
            pacc_out[2 * j] = accA[r];
            pacc_out[2 * j + 1] = accB[r];
        }
    }
}

// ---------------- nearest pooled node: chunked partial argmin via packed u64 ----------------
__global__ void k_near_part(const float* __restrict__ x, const float* __restrict__ selpos,
                            unsigned long long* __restrict__ best, int n) {
    __shared__ float2 sp[CHUNK];
    const int j0 = blockIdx.y * CHUNK;
    for (int j = threadIdx.x; j < CHUNK; j += blockDim.x)
        sp[j] = ((const float2*)selpos)[j0 + j];
    __syncthreads();
    int i = blockIdx.x * blockDim.x + threadIdx.x;
    if (i >= n) return;
    float px = x[i * FIN + 14], py = x[i * FIN + 15];
    float bd = 3.4e38f; int bj = 0;
#pragma unroll 2
    for (int j = 0; j < CHUNK; ++j) {
        float dx = px - sp[j].x, dy = py - sp[j].y;
        float d = fmaf(dx, dx, dy * dy);
        if (d < bd) { bd = d; bj = j0 + j; }
    }
    unsigned long long pk = ((unsigned long long)__float_as_uint(bd) << 32) | (unsigned)bj;
    atomicMin(&best[i], pk);
}

// ---------------- final linear (74 -> 10) ----------------
__global__ void k_final(const float* __restrict__ x1, const float* __restrict__ x2,
                        const float* __restrict__ xp2, const unsigned long long* __restrict__ best,
                        const float* __restrict__ W3, const float* __restrict__ b3,
                        float* __restrict__ o, int n) {
    __shared__ float sW[740], sb[10];
    for (int i = threadIdx.x; i < 740; i += blockDim.x) sW[i] = W3[i];
    if (threadIdx.x < 10) sb[threadIdx.x] = b3[threadIdx.x];
    __syncthreads();
    int t = blockIdx.x * blockDim.x + threadIdx.x;
    if (t >= n * 10) return;
    int i = t / 10, c = t - 10 * (t / 10);
    float s = sb[c];
    const float* r1 = &x1[i * H1];
#pragma unroll
    for (int f = 0; f < H1; ++f) s = fmaf(r1[f], sW[f * 10 + c], s);
    const float* r2 = &x2[i * H2];
#pragma unroll
    for (int f = 0; f < H2; ++f) s = fmaf(r2[f], sW[(H1 + f) * 10 + c], s);
    int m = (int)(best[i] & 0xFFFFFFFFull);
    s = fmaf(xp2[m * 2],     sW[720 + c], s);
    s = fmaf(xp2[m * 2 + 1], sW[730 + c], s);
    o[t] = s;
}

// =====================================================================
extern "C" void kernel_launch(void* const* d_in, const int* in_sizes, int n_in,
                              void* d_out, int out_size, void* d_ws, size_t ws_size,
                              hipStream_t stream) {
    const float* x   = (const float*)d_in[0];
    const int*   ei  = (const int*)d_in[1];
    const int*   src = ei;
    const int*   dst = ei + NE;
    const float* W1  = (const float*)d_in[2];
    const float* b1  = (const float*)d_in[3];
    const float* W2  = (const float*)d_in[4];
    const float* b2  = (const float*)d_in[5];
    const float* g1  = (const float*)d_in[6];
    const float* be1 = (const float*)d_in[7];
    const float* g2  = (const float*)d_in[8];
    const float* be2 = (const float*)d_in[9];
    const float* Wc  = (const float*)d_in[10];
    const float* bc  = (const float*)d_in[11];
    const float* pw  = (const float*)d_in[12];
    const float* Wp  = (const float*)d_in[13];
    const float* bp  = (const float*)d_in[14];
    const float* W3  = (const float*)d_in[15];
    const float* b3  = (const float*)d_in[16];
    float* out = (float*)d_out;

    // ---- workspace layout ----
    char* w = (char*)d_ws;
    auto alloc = [&](size_t bytes) -> void* {
        void* p = (void*)w;
        w += (bytes + 255) & ~(size_t)255;
        return p;
    };
    int*   cnt_dst  = (int*)alloc(NN * 4);
    float* dinv     = (float*)alloc(NN * 4);
    int*   rowstart = (int*)alloc((NN + 1) * 4);
    int*   rank     = (int*)alloc((size_t)NE * 4);
    int2*  csr      = (int2*)alloc((size_t)NE * 8);
    float* B1    = (float*)alloc((size_t)NN * H1 * 4);
    float* B2    = (float*)alloc((size_t)NN * H1 * 4);
    float* B3    = (float*)alloc((size_t)NN * H1 * 4);
    float* acc   = (float*)alloc((size_t)NN * H1 * 4);
    float* x1    = (float*)alloc((size_t)NN * H1 * 4);
    float* x2    = (float*)alloc((size_t)NN * H2 * 4);
    float* xc    = (float*)alloc((size_t)NN * 2 * 4);
    float* score = (float*)alloc(NN * 4);
    float* stats = (float*)alloc(144 * 4);   // stats1 = +0, stats2 = +72 (zeroed in k_red)
    unsigned* key   = (unsigned*)alloc(NN * 4);
    int* nidx       = (int*)alloc(NN * 4);
    int* sel        = (int*)alloc(KSEL * 4);
    unsigned long long* best = (unsigned long long*)alloc(NN * 8);
    unsigned* Tptr  = (unsigned*)alloc(4);
    int* Rptr       = (int*)alloc(4);
    unsigned* BinPtr = (unsigned*)alloc(4);
    int* RemPtr     = (int*)alloc(4);
    int* gh         = (int*)alloc(2 * 65536 * 4);   // adjacent to pcnt (one memset)
    int* pcnt       = (int*)alloc(KSEL * 4);
    int* bgt        = (int*)alloc(64 * 4);
    int* beq        = (int*)alloc(64 * 4);
    int* eqoff      = (int*)alloc(64 * 4);
    int* soff       = (int*)alloc(64 * 4);
    int* lens       = (int*)alloc(KSEL * 4);
    int* prs        = (int*)alloc((KSEL + 1) * 4);
    float* dinvp    = (float*)alloc(KSEL * 4);
    int2* gcsr      = (int2*)alloc((size_t)PCAP * 8);
    float* pacc     = (float*)alloc(KSEL * 2 * 4);
    float* selpos   = (float*)alloc(KSEL * 2 * 4);

    float* stats1 = stats;
    float* stats2 = stats + 72;

    // partials overlay B1..B2 (7.68 MB < 8.64 MB contiguous); fully consumed
    // by k_fill3 before conv1's first k_prop_gemm writes B1.
    int* partials = (int*)B1;   // [2][NB_H][NN]

    const int NBK = (NN + 63) / 64;
    const int CSB = 117;  // colstats grid: 117*256 = 29952, divisible by 36

    // ---- initial memsets (gh+pcnt adjacent -> single fill) ----
    hipMemsetAsync(gh, 0, 2 * 65536 * 4 + ((KSEL * 4 + 255) & ~255), stream);
    hipMemsetAsync(best, 0xFF, NN * 8, stream);

    // ---- degree + CSR build (LDS histograms + rank; atomic-free fill) ----
    {
        dim3 gh2(NB_H, 2);
        k_hist<<<gh2, 1024, 0, stream>>>(src, dst, partials, rank);
        k_red<<<nb(NN), TPB, 0, stream>>>(partials, dinv, cnt_dst, stats);
        k_scan<<<1, 1024, 0, stream>>>(cnt_dst, rowstart, NN);
        k_fill3<<<nb(NE), TPB, 0, stream>>>(src, dst, rank, dinv, rowstart,
                                            partials + (size_t)NB_H * NN, csr, NE);
    }

    // ---- conv1: K=8, 16 -> 36 (first hop fused with W0 GEMM + bias) ----
    {
        float* rot[3] = {B1, B2, B3};
        k_prop_gemm<FIN, H1, 64, true><<<NBK, 64 * (FIN / 4), 0, stream>>>(
            rowstart, csr, x, nullptr, W1 + FIN * H1, W1, b1, B1, acc, NN);
        const float* t_prev = x; const float* t_cur = B1;
        for (int kk = 2; kk < KHOP; ++kk) {
            float* o = rot[(kk - 1) % 3];
            k_prop_gemm<FIN, H1, 64, false><<<NBK, 64 * (FIN / 4), 0, stream>>>(
                rowstart, csr, t_cur, t_prev, W1 + kk * FIN * H1, nullptr, nullptr, o, acc, NN);
            t_prev = t_cur; t_cur = o;
        }
        k_colstats<H1><<<CSB, TPB, 0, stream>>>(acc, stats1, NN);
        k_bn<H1><<<nb((long long)NN * H1), TPB, 0, stream>>>(acc, stats1, g1, be1, x1, NN);
    }

    // ---- conv2: K=8, 36 -> 36 (first hop fused) ----
    {
        float* rot[3] = {B1, B2, B3};
        k_prop_gemm<H1, H2, 64, true><<<NBK, 64 * (H1 / 4), 0, stream>>>(
            rowstart, csr, x1, nullptr, W2 + H1 * H2, W2, b2, B1, acc, NN);
        const float* t_prev = x1; const float* t_cur = B1;
        for (int kk = 2; kk < KHOP; ++kk) {
            float* o = rot[(kk - 1) % 3];
            k_prop_gemm<H1, H2, 64, false><<<NBK, 64 * (H1 / 4), 0, stream>>>(
                rowstart, csr, t_cur, t_prev, W2 + kk * H1 * H2, nullptr, nullptr, o, acc, NN);
            t_prev = t_cur; t_cur = o;
        }
        k_colstats<H2><<<CSB, TPB, 0, stream>>>(acc, stats2, NN);
        k_bn<H2><<<nb((long long)NN * H2), TPB, 0, stream>>>(acc, stats2, g2, be2, x2, NN);
    }

    // ---- xc, score, key + first 16-bit histogram (fused) ----
    k_xc_score<<<nb(NN), TPB, 0, stream>>>(x1, Wc, bc, pw, xc, score, key, gh, NN);

    // ---- top-k threshold (parallel 2x16-bit radix) ----
    k_scanhist<<<1, 1024, 0, stream>>>(gh, nullptr, KSEL, nullptr, BinPtr, RemPtr);
    k_h16b<<<nb(NN), TPB, 0, stream>>>(key, BinPtr, gh + 65536, NN);
    k_scanhist<<<1, 1024, 0, stream>>>(gh + 65536, RemPtr, 0, BinPtr, Tptr, Rptr);

    // ---- parallel select (ascending-index order) ----
    {
        const int SB = (NN + 1023) / 1024;   // 30 blocks
        k_selcnt<<<SB, 1024, 0, stream>>>(key, Tptr, bgt, beq, NN);
        k_seloff<<<1, 64, 0, stream>>>(bgt, beq, Rptr, eqoff, soff, SB);
        k_selfill<<<SB, 1024, 0, stream>>>(key, Tptr, Rptr, eqoff, soff, nidx, sel, NN);
    }

    // ---- pooled graph build (parallel) ----
    {
        const int WPB = TPB / 64;
        const int GB = (KSEL + WPB - 1) / WPB;
        k_plen<<<GB, TPB, 0, stream>>>(rowstart, csr, nidx, sel, pcnt, lens);
        k_scan_pool<<<1, 1024, 0, stream>>>(lens, prs, pcnt, dinvp);
        k_pfill<<<GB, TPB, 0, stream>>>(rowstart, csr, nidx, sel, dinvp, prs, gcsr);
    }

    // ---- pooled 7-hop pipeline (LDS-resident) ----
    k_pooled4<<<1, 1024, 0, stream>>>(prs, gcsr, sel, xc, score, x, Wp, bp, pacc, selpos);

    // ---- nearest pooled node (chunked), final linear ----
    {
        dim3 g(nb(NN), NCHUNK);
        k_near_part<<<g, TPB, 0, stream>>>(x, selpos, best, NN);
    }
    k_final<<<nb((long long)NN * 10), TPB, 0, stream>>>(x1, x2, pacc, best, W3, b3, out, NN);
}

// Round 15
// 499.554 us; speedup vs baseline: 1.1129x; 1.0090x over previous
//
#include <hip/hip_runtime.h>
#include <cstdint>

constexpr int NN   = 30000;
constexpr int NE   = 960000;
constexpr int FIN  = 16;
constexpr int H1   = 36;
constexpr int H2   = 36;
constexpr int KHOP = 8;
constexpr int KSEL = 3000;   // ceil(0.1 * 30000)
constexpr int PCAP = 32768;  // pooled-edge capacity (expected ~9600)
constexpr int NCHUNK = 12;   // candidate chunks for nearest (3000/12 = 250)
constexpr int CHUNK = KSEL / NCHUNK;
constexpr int NB_H = 32;     // histogram blocks
constexpr int EPB  = (NE + NB_H - 1) / NB_H;   // edges per histogram block (30000)
constexpr float EPSV = 1e-5f;

#define TPB 256

static inline int nb(long long t) { return (int)((t + TPB - 1) / TPB); }

// ---------------- LDS histogram: partials[y][b][j]; dst pass also records rank ----------------
__global__ __launch_bounds__(1024)
void k_hist(const int* __restrict__ src, const int* __restrict__ dst,
            int* __restrict__ partials, int* __restrict__ rank) {
    __shared__ int hist[NN];   // 120 KB
    for (int j = threadIdx.x; j < NN; j += 1024) hist[j] = 0;
    __syncthreads();
    int b = blockIdx.x;
    int e0 = b * EPB, e1 = min(NE, e0 + EPB);
    if (blockIdx.y == 0) {
        for (int e = e0 + (int)threadIdx.x; e < e1; e += 1024)
            atomicAdd(&hist[src[e]], 1);
    } else {
        for (int e = e0 + (int)threadIdx.x; e < e1; e += 1024)
            rank[e] = atomicAdd(&hist[dst[e]], 1);
    }
    __syncthreads();
    int* P = partials + ((size_t)blockIdx.y * NB_H + b) * NN;
    for (int j = threadIdx.x; j < NN; j += 1024) P[j] = hist[j];
}

// ---------------- reduce partials: dinv (src), per-block exclusive offsets + cnt_dst
//                   also zeroes the BN-stats buffer (144 floats) ----------------
__global__ void k_red(int* __restrict__ partials, float* __restrict__ dinv,
                      int* __restrict__ cnt_dst, float* __restrict__ stats) {
    if (blockIdx.x == 0 && threadIdx.x < 144) stats[threadIdx.x] = 0.f;
    int j = blockIdx.x * blockDim.x + threadIdx.x;
    if (j >= NN) return;
    const int* Ps = partials;
    int s = 0;
#pragma unroll
    for (int b = 0; b < NB_H; ++b) s += Ps[(size_t)b * NN + j];
    dinv[j] = s > 0 ? rsqrtf((float)s) : 0.0f;
    int* Pd = partials + (size_t)NB_H * NN;
    int run = 0;
#pragma unroll
    for (int b = 0; b < NB_H; ++b) {
        int t = Pd[(size_t)b * NN + j];
        Pd[(size_t)b * NN + j] = run;
        run += t;
    }
    cnt_dst[j] = run;
}

// ---------------- block scan helper (blockDim must be 1024) ----------------
__device__ __forceinline__ int block_scan_excl_1024(int val, int& total) {
    __shared__ int wsum[16];
    int tid = threadIdx.x, lane = tid & 63, wv = tid >> 6;
    int v = val;
#pragma unroll
    for (int off = 1; off < 64; off <<= 1) {
        int t = __shfl_up(v, off, 64);
        if (lane >= off) v += t;
    }
    __syncthreads();
    if (lane == 63) wsum[wv] = v;
    __syncthreads();
    if (tid < 16) {
        int w = wsum[tid];
#pragma unroll
        for (int off = 1; off < 16; off <<= 1) {
            int t = __shfl_up(w, off, 64);
            if (tid >= off) w += t;
        }
        wsum[tid] = w;
    }
    __syncthreads();
    int base = (wv > 0) ? wsum[wv - 1] : 0;
    total = wsum[15];
    return base + v - val;
}

__global__ void k_scan(const int* __restrict__ cnt, int* __restrict__ rowstart, int n) {
    __shared__ int run;
    if (threadIdx.x == 0) run = 0;
    __syncthreads();
    for (int base = 0; base < n; base += 1024) {
        int i = base + threadIdx.x;
        int v = (i < n) ? cnt[i] : 0;
        int tot; int ex = block_scan_excl_1024(v, tot);
        int r = run;
        if (i < n) rowstart[i] = r + ex;
        __syncthreads();
        if (threadIdx.x == 0) run += tot;
        __syncthreads();
    }
    if (threadIdx.x == 0) rowstart[n] = run;
}

// scan for pooled lens (n = KSEL) + fused pooled dinv from pcnt
__global__ __launch_bounds__(1024)
void k_scan_pool(const int* __restrict__ lens, int* __restrict__ prs,
                 const int* __restrict__ pcnt, float* __restrict__ dinvp) {
    __shared__ int run;
    if (threadIdx.x == 0) run = 0;
    __syncthreads();
    for (int base = 0; base < KSEL; base += 1024) {
        int i = base + threadIdx.x;
        int v = (i < KSEL) ? lens[i] : 0;
        int tot; int ex = block_scan_excl_1024(v, tot);
        int r = run;
        if (i < KSEL) prs[i] = r + ex;
        __syncthreads();
        if (threadIdx.x == 0) run += tot;
        __syncthreads();
    }
    if (threadIdx.x == 0) prs[KSEL] = run;
    for (int j = threadIdx.x; j < KSEL; j += 1024) {
        int c = pcnt[j];
        dinvp[j] = c > 0 ? rsqrtf((float)c) : 0.0f;
    }
}

// ---------------- CSR fill: pure function of precomputed rank (no atomics, no LDS) ----------------
__global__ void k_fill3(const int* __restrict__ src, const int* __restrict__ dst,
                        const int* __restrict__ rank, const float* __restrict__ dinv,
                        const int* __restrict__ rowstart, const int* __restrict__ Pd_excl,
                        int2* __restrict__ csr, int E) {
    int e = blockIdx.x * blockDim.x + threadIdx.x;
    if (e >= E) return;
    int s = src[e], d = dst[e];
    int b = e / EPB;
    int pos = rowstart[d] + Pd_excl[(size_t)b * NN + d] + rank[e];
    float w = -dinv[s] * dinv[d];
    csr[pos] = make_int2(s, __float_as_int(w));
}

// ---------------- fused prop+GEMM with LDS-staged edge range, optional first-hop W0 fusion ----------------
// FIRST: t1 = A^ h ; acc = bias + h@W0 + t1@Wk   (t0 unused)
// else : t_k = 2*A^ h - t0 ; acc += t_k@Wk
// LAST : skip the global tout write (t_K only feeds acc via the LDS tile)
#define PROP_BODY(EDGE_AT)                                                    \
    for (; e + 3 < e1; e += 4) {                                              \
        int2 ea = EDGE_AT(e);                                                 \
        int2 eb = EDGE_AT(e + 1);                                             \
        int2 ec = EDGE_AT(e + 2);                                             \
        int2 ed = EDGE_AT(e + 3);                                             \
        float4 ha = h4[ea.x * QF + q];                                        \
        float4 hb = h4[eb.x * QF + q];                                        \
        float4 hc = h4[ec.x * QF + q];                                        \
        float4 hd = h4[ed.x * QF + q];                                        \
        float wa = __int_as_float(ea.y), wb = __int_as_float(eb.y);           \
        float wc = __int_as_float(ec.y), wd = __int_as_float(ed.y);           \
        p.x = fmaf(wa, ha.x, p.x); p.y = fmaf(wa, ha.y, p.y);                 \
        p.z = fmaf(wa, ha.z, p.z); p.w = fmaf(wa, ha.w, p.w);                 \
        p.x = fmaf(wb, hb.x, p.x); p.y = fmaf(wb, hb.y, p.y);                 \
        p.z = fmaf(wb, hb.z, p.z); p.w = fmaf(wb, hb.w, p.w);                 \
        p.x = fmaf(wc, hc.x, p.x); p.y = fmaf(wc, hc.y, p.y);                 \
        p.z = fmaf(wc, hc.z, p.z); p.w = fmaf(wc, hc.w, p.w);                 \
        p.x = fmaf(wd, hd.x, p.x); p.y = fmaf(wd, hd.y, p.y);                 \
        p.z = fmaf(wd, hd.z, p.z); p.w = fmaf(wd, hd.w, p.w);                 \
    }                                                                         \
    for (; e < e1; ++e) {                                                     \
        int2 ew = EDGE_AT(e);                                                 \
        float w = __int_as_float(ew.y);                                       \
        float4 hv = h4[ew.x * QF + q];                                        \
        p.x = fmaf(w, hv.x, p.x); p.y = fmaf(w, hv.y, p.y);                   \
        p.z = fmaf(w, hv.z, p.z); p.w = fmaf(w, hv.w, p.w);                   \
    }

template<int F, int O, int BN, bool FIRST, bool LAST>
__global__ __launch_bounds__(BN * F / 4)
void k_prop_gemm(const int* __restrict__ rowstart, const int2* __restrict__ csr,
                 const float* __restrict__ h, const float* __restrict__ t0,
                 const float* __restrict__ Wk, const float* __restrict__ W0,
                 const float* __restrict__ bias, float* __restrict__ tout,
                 float* __restrict__ acc, int n) {
    constexpr int QF = F / 4;
    constexpr int NT = BN * QF;
    constexpr int ECAP = 2560;   // block edge-count ~Poisson(2048), sigma~45; >11 sigma margin
    __shared__ float sT[BN * F];
    __shared__ float sW[F * O];
    __shared__ float sW0[FIRST ? F * O : 1];
    __shared__ float sX[FIRST ? BN * F : 1];
    __shared__ int2  sE[ECAP];
    const int tid = threadIdx.x;
    for (int i = tid; i < F * O; i += NT) sW[i] = Wk[i];
    if (FIRST) {
        for (int i = tid; i < F * O; i += NT) sW0[i] = W0[i];
        int base = blockIdx.x * BN * F;
        int lim = min(BN * F, n * F - base);
        for (int i = tid; i < lim; i += NT) sX[i] = h[base + i];
    }
    const int rowLo = blockIdx.x * BN;
    const int rowHi = min(n, rowLo + BN);
    const int e0b = rowstart[rowLo];
    const int ecnt = rowstart[rowHi] - e0b;
    const bool staged = (ecnt <= ECAP);
    if (staged) {
        for (int i = tid; i < ecnt; i += NT) sE[i] = csr[e0b + i];
    }
    __syncthreads();
    const int nl = tid / QF, q = tid - nl * QF;
    const int node = rowLo + nl;
    if (node < n) {
        const float4* __restrict__ h4 = (const float4*)h;
        float4 p = {0.f, 0.f, 0.f, 0.f};
        int e0g = rowstart[node], e1g = rowstart[node + 1];
        if (staged) {
            int e = e0g - e0b, e1 = e1g - e0b;
#define EDGE_LDS(idx) sE[idx]
            PROP_BODY(EDGE_LDS)
#undef EDGE_LDS
        } else {
            int e = e0g, e1 = e1g;
#define EDGE_GBL(idx) csr[idx]
            PROP_BODY(EDGE_GBL)
#undef EDGE_GBL
        }
        if (!FIRST) {
            float4 tv = ((const float4*)t0)[node * QF + q];
            p.x = 2.f * p.x - tv.x; p.y = 2.f * p.y - tv.y;
            p.z = 2.f * p.z - tv.z; p.w = 2.f * p.w - tv.w;
        }
        if (!LAST) ((float4*)tout)[node * QF + q] = p;
        sT[nl * F + 4 * q + 0] = p.x; sT[nl * F + 4 * q + 1] = p.y;
        sT[nl * F + 4 * q + 2] = p.z; sT[nl * F + 4 * q + 3] = p.w;
    }
    __syncthreads();
    for (int idx = tid; idx < BN * O; idx += NT) {
        int nl2 = idx / O, o = idx - nl2 * O;
        int gn = rowLo + nl2;
        if (gn >= n) break;
        float s;
        if (FIRST) {
            s = bias[o];
#pragma unroll
            for (int f = 0; f < F; ++f) s = fmaf(sX[nl2 * F + f], sW0[f * O + o], s);
        } else {
            s = 0.f;
        }
#pragma unroll
        for (int f = 0; f < F; ++f) s = fmaf(sT[nl2 * F + f], sW[f * O + o], s);
        if (FIRST) acc[gn * O + o] = s;
        else       acc[gn * O + o] += s;
    }
}

// ---------------- relu + batchnorm stats: fixed-channel register accumulation ----------------
// REQUIRES gridDim.x * blockDim.x % C == 0  (stride-preserving channel)
template<int C>
__global__ void k_colstats(const float* __restrict__ a, float* __restrict__ stats, int n) {
    __shared__ float b1[C], b2[C];
    for (int i = threadIdx.x; i < C; i += blockDim.x) { b1[i] = 0.f; b2[i] = 0.f; }
    __syncthreads();
    int t0 = blockIdx.x * blockDim.x + threadIdx.x;
    int stride = gridDim.x * blockDim.x;
    int c = t0 % C;
    float s1 = 0.f, s2 = 0.f;
    for (int t = t0; t < n * C; t += stride) {
        float v = fmaxf(a[t], 0.f);
        s1 += v; s2 = fmaf(v, v, s2);
    }
    atomicAdd(&b1[c], s1); atomicAdd(&b2[c], s2);
    __syncthreads();
    for (int i = threadIdx.x; i < C; i += blockDim.x) {
        atomicAdd(&stats[i], b1[i]); atomicAdd(&stats[C + i], b2[i]);
    }
}

template<int C>
__global__ void k_bn(const float* __restrict__ a, const float* __restrict__ stats,
                     const float* __restrict__ g, const float* __restrict__ be,
                     float* __restrict__ o, int n) {
    int t = blockIdx.x * blockDim.x + threadIdx.x;
    if (t >= n * C) return;
    int c = t % C;
    float mu = stats[c] / n;
    float var = stats[C + c] / n - mu * mu;
    float v = fmaxf(a[t], 0.f);
    o[t] = (v - mu) * rsqrtf(var + EPSV) * g[c] + be[c];
}

// ---------------- xc, score, sortable key + first top-k histogram + best-init (fused) ----------------
__global__ void k_xc_score(const float* __restrict__ x1, const float* __restrict__ Wc,
                           const float* __restrict__ bc, const float* __restrict__ pw,
                           float* __restrict__ xc, float* __restrict__ score,
                           unsigned* __restrict__ key, int* __restrict__ gh,
                           unsigned long long* __restrict__ best, int n) {
    int i = blockIdx.x * blockDim.x + threadIdx.x;
    if (i >= n) return;
    best[i] = ~0ull;   // init for k_near_part's atomicMin (runs much later)
    const float* r = &x1[i * H1];
    float a = bc[0], b = bc[1];
#pragma unroll
    for (int f = 0; f < H1; ++f) { float v = r[f]; a = fmaf(v, Wc[f * 2], a); b = fmaf(v, Wc[f * 2 + 1], b); }
    xc[i * 2] = a; xc[i * 2 + 1] = b;
    float w0 = pw[0], w1 = pw[1];
    float s = tanhf((a * w0 + b * w1) / sqrtf(w0 * w0 + w1 * w1));
    score[i] = s;
    unsigned u = __float_as_uint(s);
    unsigned k = (u & 0x80000000u) ? ~u : (u | 0x80000000u);
    key[i] = k;
    atomicAdd(&gh[k >> 16], 1);
}

__global__ void k_h16b(const unsigned* __restrict__ key, const unsigned* __restrict__ pB,
                       int* __restrict__ gh, int n) {
    unsigned B = *pB;
    int i = blockIdx.x * blockDim.x + threadIdx.x;
    if (i < n && (key[i] >> 16) == B) atomicAdd(&gh[key[i] & 0xFFFFu], 1);
}

// descending scan over 65536-bin histogram: find bin with cum-from-top crossing k.
__global__ __launch_bounds__(1024)
void k_scanhist(const int* __restrict__ hist, const int* __restrict__ kin, int kdef,
                const unsigned* __restrict__ prevBin, unsigned* __restrict__ outT,
                int* __restrict__ outRem) {
    __shared__ int cs[1024];
    __shared__ int sC, sAbove;
    const int tid = threadIdx.x;
    int k = kin ? *kin : kdef;
    int s = 0;
    int base = tid * 64;
#pragma unroll 8
    for (int j = 0; j < 64; ++j) s += hist[base + j];
    cs[tid] = s;
    __syncthreads();
    int rsum = cs[1023 - tid];
    int tot; int ex = block_scan_excl_1024(rsum, tot);
    int c = 1023 - tid;
    if (ex < k && ex + cs[c] >= k) { sC = c; sAbove = ex; }
    __syncthreads();
    if (tid < 64) {
        int bin = sC * 64 + 63 - tid;
        int val = hist[bin];
        int incl = val;
#pragma unroll
        for (int off = 1; off < 64; off <<= 1) {
            int t2 = __shfl_up(incl, off, 64);
            if (tid >= off) incl += t2;
        }
        int above2 = sAbove + (incl - val);
        if (above2 < k && above2 + val >= k) {
            if (prevBin) *outT = ((*prevBin) << 16) | (unsigned)bin;
            else         *outT = (unsigned)bin;
            *outRem = k - above2;
        }
    }
}

// ---------------- parallel select (ascending-index order, eq-quota r) ----------------
__global__ __launch_bounds__(1024)
void k_selcnt(const unsigned* __restrict__ key, const unsigned* __restrict__ pT,
              int* __restrict__ bgt, int* __restrict__ beq, int n) {
    __shared__ int sgt, seq;
    if (threadIdx.x == 0) { sgt = 0; seq = 0; }
    __syncthreads();
    unsigned T = *pT;
    int i = blockIdx.x * 1024 + threadIdx.x;
    if (i < n) {
        unsigned kk = key[i];
        if (kk > T) atomicAdd(&sgt, 1);
        else if (kk == T) atomicAdd(&seq, 1);
    }
    __syncthreads();
    if (threadIdx.x == 0) { bgt[blockIdx.x] = sgt; beq[blockIdx.x] = seq; }
}

__global__ void k_seloff(const int* __restrict__ bgt, const int* __restrict__ beq,
                         const int* __restrict__ pR, int* __restrict__ eqoff,
                         int* __restrict__ soff, int nblk) {
    int t = threadIdx.x;
    int g = (t < nblk) ? bgt[t] : 0;
    int q = (t < nblk) ? beq[t] : 0;
    int gi = g, qi = q;
#pragma unroll
    for (int off = 1; off < 64; off <<= 1) {
        int a = __shfl_up(gi, off, 64);
        int b = __shfl_up(qi, off, 64);
        if (t >= off) { gi += a; qi += b; }
    }
    int qex = qi - q;
    int r = *pR;
    int eqsel = min(max(r - qex, 0), q);
    int scnt = g + eqsel;
    int si = scnt;
#pragma unroll
    for (int off = 1; off < 64; off <<= 1) {
        int a = __shfl_up(si, off, 64);
        if (t >= off) si += a;
    }
    if (t < nblk) { eqoff[t] = qex; soff[t] = si - scnt; }
}

__global__ __launch_bounds__(1024)
void k_selfill(const unsigned* __restrict__ key, const unsigned* __restrict__ pT,
               const int* __restrict__ pR, const int* __restrict__ eqoff,
               const int* __restrict__ soff, int* __restrict__ nidx,
               int* __restrict__ sel, int n) {
    unsigned T = *pT; int r = *pR;
    int b = blockIdx.x;
    int i = b * 1024 + threadIdx.x;
    unsigned kk = (i < n) ? key[i] : 0u;
    int eq = (i < n && kk == T) ? 1 : 0;
    int gt = (i < n && kk > T) ? 1 : 0;
    int eq_tot; int eq_ex = block_scan_excl_1024(eq, eq_tot);
    int sf = gt | (eq & (((eqoff[b] + eq_ex) < r) ? 1 : 0));
    int s_tot; int s_ex = block_scan_excl_1024(sf, s_tot);
    if (i < n) {
        if (sf) { int slot = soff[b] + s_ex; nidx[i] = slot; sel[slot] = i; }
        else nidx[i] = -1;
    }
}

// ---------------- pooled build: one wave per pooled row ----------------
__global__ void k_plen(const int* __restrict__ m_rowstart, const int2* __restrict__ m_csr,
                       const int* __restrict__ nidx, const int* __restrict__ sel,
                       int* __restrict__ pcnt, int* __restrict__ lens) {
    int wid = (blockIdx.x * blockDim.x + threadIdx.x) >> 6;
    int lane = threadIdx.x & 63;
    if (wid >= KSEL) return;
    int node = sel[wid];
    int e0 = m_rowstart[node], e1 = m_rowstart[node + 1];
    int cnt = 0;
    for (int e = e0 + lane; e < e1; e += 64) {
        int vs = nidx[m_csr[e].x];
        if (vs >= 0) { ++cnt; atomicAdd(&pcnt[vs], 1); }
    }
#pragma unroll
    for (int off = 32; off; off >>= 1) cnt += __shfl_down(cnt, off, 64);
    if (lane == 0) lens[wid] = cnt;
}

__global__ void k_pfill(const int* __restrict__ m_rowstart, const int2* __restrict__ m_csr,
                        const int* __restrict__ nidx, const int* __restrict__ sel,
                        const float* __restrict__ dinvp, const int* __restrict__ prs,
                        int2* __restrict__ gcsr) {
    int wid = (blockIdx.x * blockDim.x + threadIdx.x) >> 6;
    int lane = threadIdx.x & 63;
    if (wid >= KSEL) return;
    int node = sel[wid];
    int e0 = m_rowstart[node], e1 = m_rowstart[node + 1];
    float dd = dinvp[wid];
    int pos = prs[wid];
    for (int base = e0; base < e1; base += 64) {
        int e = base + lane;
        int vs = -1;
        if (e < e1) vs = nidx[m_csr[e].x];
        bool valid = vs >= 0;
        unsigned long long mask = __ballot(valid);
        if (valid) {
            int myoff = __popcll(mask & ((1ull << lane) - 1ull));
            float w = -dinvp[vs] * dd;
            gcsr[pos + myoff] = make_int2(vs, __float_as_int(w));
        }
        pos += __popcll(mask);
    }
}

// ---------------- pooled 7-hop Chebyshev, LDS-resident (single block) ----------------
__global__ __launch_bounds__(1024)
void k_pooled4(const int* __restrict__ prs_g, const int2* __restrict__ gcsr,
               const int* __restrict__ sel, const float* __restrict__ xc,
               const float* __restrict__ score, const float* __restrict__ x,
               const float* __restrict__ Wp, const float* __restrict__ bp,
               float* __restrict__ pacc_out, float* __restrict__ selpos) {
    __shared__ float bufA[2 * KSEL];         // 24 KB
    __shared__ float bufB[2 * KSEL];         // 24 KB
    __shared__ int   prs[KSEL + 1];          // 12 KB
    const int tid = threadIdx.x, NT = 1024;

    for (int j = tid; j <= KSEL; j += NT) prs[j] = prs_g[j];

    const float bp0 = bp[0], bp1 = bp[1];
    float accA[3], accB[3];
#pragma unroll
    for (int r = 0; r < 3; ++r) {
        int j = tid + r * NT;
        accA[r] = 0.f; accB[r] = 0.f;
        if (j < KSEL) {
            int i = sel[j];
            float s = score[i];
            float a = xc[2 * i] * s, b = xc[2 * i + 1] * s;
            bufA[2 * j] = a; bufA[2 * j + 1] = b;
            accA[r] = bp0 + a * Wp[0] + b * Wp[2];
            accB[r] = bp1 + a * Wp[1] + b * Wp[3];
            selpos[2 * j] = x[i * FIN + 14];
            selpos[2 * j + 1] = x[i * FIN + 15];
        }
    }
    __syncthreads();

    for (int k = 1; k < KHOP; ++k) {
        float* rb = (k & 1) ? bufA : bufB;
        float* wb = (k & 1) ? bufB : bufA;
        float w0 = Wp[k * 4 + 0], w1 = Wp[k * 4 + 1];
        float w2 = Wp[k * 4 + 2], w3 = Wp[k * 4 + 3];
#pragma unroll
        for (int r = 0; r < 3; ++r) {
            int j = tid + r * NT;
            if (j < KSEL) {
                float pa = 0.f, pb = 0.f;
                int e0 = prs[j], e1 = prs[j + 1];
                for (int e = e0; e < e1; ++e) {
                    int2 ew = gcsr[e];
                    float w = __int_as_float(ew.y);
                    pa = fmaf(w, rb[2 * ew.x], pa);
                    pb = fmaf(w, rb[2 * ew.x + 1], pb);
                }
                if (k >= 2) {
                    pa = 2.f * pa - wb[2 * j];
                    pb = 2.f * pb - wb[2 * j + 1];
                }
                wb[2 * j] = pa; wb[2 * j + 1] = pb;
                accA[r] = fmaf(pa, w0, fmaf(pb, w2, accA[r]));
                accB[r] = fmaf(pa, w1, fmaf(pb, w3, accB[r]));
            }
        }
        __syncthreads();
    }

#pragma unroll
    for (int r = 0; r < 3; ++r) {
        int j = tid + r * NT;
        if (j < KSEL) {
            pacc_out[2 * j] = accA[r];
            pacc_out[2 * j + 1] = accB[r];
        }
    }
}

// ---------------- nearest pooled node: chunked partial argmin via packed u64 ----------------
__global__ void k_near_part(const float* __restrict__ x, const float* __restrict__ selpos,
                            unsigned long long* __restrict__ best, int n) {
    __shared__ float2 sp[CHUNK];
    const int j0 = blockIdx.y * CHUNK;
    for (int j = threadIdx.x; j < CHUNK; j += blockDim.x)
        sp[j] = ((const float2*)selpos)[j0 + j];
    __syncthreads();
    int i = blockIdx.x * blockDim.x + threadIdx.x;
    if (i >= n) return;
    float px = x[i * FIN + 14], py = x[i * FIN + 15];
    float bd = 3.4e38f; int bj = 0;
#pragma unroll 2
    for (int j = 0; j < CHUNK; ++j) {
        float dx = px - sp[j].x, dy = py - sp[j].y;
        float d = fmaf(dx, dx, dy * dy);
        if (d < bd) { bd = d; bj = j0 + j; }
    }
    unsigned long long pk = ((unsigned long long)__float_as_uint(bd) << 32) | (unsigned)bj;
    atomicMin(&best[i], pk);
}

// ---------------- final linear (74 -> 10) ----------------
__global__ void k_final(const float* __restrict__ x1, const float* __restrict__ x2,
                        const float* __restrict__ xp2, const unsigned long long* __restrict__ best,
                        const float* __restrict__ W3, const float* __restrict__ b3,
                        float* __restrict__ o, int n) {
    __shared__ float sW[740], sb[10];
    for (int i = threadIdx.x; i < 740; i += blockDim.x) sW[i] = W3[i];
    if (threadIdx.x < 10) sb[threadIdx.x] = b3[threadIdx.x];
    __syncthreads();
    int t = blockIdx.x * blockDim.x + threadIdx.x;
    if (t >= n * 10) return;
    int i = t / 10, c = t - 10 * (t / 10);
    float s = sb[c];
    const float* r1 = &x1[i * H1];
#pragma unroll
    for (int f = 0; f < H1; ++f) s = fmaf(r1[f], sW[f * 10 + c], s);
    const float* r2 = &x2[i * H2];
#pragma unroll
    for (int f = 0; f < H2; ++f) s = fmaf(r2[f], sW[(H1 + f) * 10 + c], s);
    int m = (int)(best[i] & 0xFFFFFFFFull);
    s = fmaf(xp2[m * 2],     sW[720 + c], s);
    s = fmaf(xp2[m * 2 + 1], sW[730 + c], s);
    o[t] = s;
}

// =====================================================================
extern "C" void kernel_launch(void* const* d_in, const int* in_sizes, int n_in,
                              void* d_out, int out_size, void* d_ws, size_t ws_size,
                              hipStream_t stream) {
    const float* x   = (const float*)d_in[0];
    const int*   ei  = (const int*)d_in[1];
    const int*   src = ei;
    const int*   dst = ei + NE;
    const float* W1  = (const float*)d_in[2];
    const float* b1  = (const float*)d_in[3];
    const float* W2  = (const float*)d_in[4];
    const float* b2  = (const float*)d_in[5];
    const float* g1  = (const float*)d_in[6];
    const float* be1 = (const float*)d_in[7];
    const float* g2  = (const float*)d_in[8];
    const float* be2 = (const float*)d_in[9];
    const float* Wc  = (const float*)d_in[10];
    const float* bc  = (const float*)d_in[11];
    const float* pw  = (const float*)d_in[12];
    const float* Wp  = (const float*)d_in[13];
    const float* bp  = (const float*)d_in[14];
    const float* W3  = (const float*)d_in[15];
    const float* b3  = (const float*)d_in[16];
    float* out = (float*)d_out;

    // ---- workspace layout ----
    char* w = (char*)d_ws;
    auto alloc = [&](size_t bytes) -> void* {
        void* p = (void*)w;
        w += (bytes + 255) & ~(size_t)255;
        return p;
    };
    int*   cnt_dst  = (int*)alloc(NN * 4);
    float* dinv     = (float*)alloc(NN * 4);
    int*   rowstart = (int*)alloc((NN + 1) * 4);
    int*   rank     = (int*)alloc((size_t)NE * 4);
    int2*  csr      = (int2*)alloc((size_t)NE * 8);
    float* B1    = (float*)alloc((size_t)NN * H1 * 4);
    float* B2    = (float*)alloc((size_t)NN * H1 * 4);
    float* B3    = (float*)alloc((size_t)NN * H1 * 4);
    float* acc   = (float*)alloc((size_t)NN * H1 * 4);
    float* x1    = (float*)alloc((size_t)NN * H1 * 4);
    float* x2    = (float*)alloc((size_t)NN * H2 * 4);
    float* xc    = (float*)alloc((size_t)NN * 2 * 4);
    float* score = (float*)alloc(NN * 4);
    float* stats = (float*)alloc(144 * 4);   // stats1 = +0, stats2 = +72 (zeroed in k_red)
    unsigned* key   = (unsigned*)alloc(NN * 4);
    int* nidx       = (int*)alloc(NN * 4);
    int* sel        = (int*)alloc(KSEL * 4);
    unsigned long long* best = (unsigned long long*)alloc(NN * 8);
    unsigned* Tptr  = (unsigned*)alloc(4);
    int* Rptr       = (int*)alloc(4);
    unsigned* BinPtr = (unsigned*)alloc(4);
    int* RemPtr     = (int*)alloc(4);
    int* gh         = (int*)alloc(2 * 65536 * 4);   // adjacent to pcnt (one memset)
    int* pcnt       = (int*)alloc(KSEL * 4);
    int* bgt        = (int*)alloc(64 * 4);
    int* beq        = (int*)alloc(64 * 4);
    int* eqoff      = (int*)alloc(64 * 4);
    int* soff       = (int*)alloc(64 * 4);
    int* lens       = (int*)alloc(KSEL * 4);
    int* prs        = (int*)alloc((KSEL + 1) * 4);
    float* dinvp    = (float*)alloc(KSEL * 4);
    int2* gcsr      = (int2*)alloc((size_t)PCAP * 8);
    float* pacc     = (float*)alloc(KSEL * 2 * 4);
    float* selpos   = (float*)alloc(KSEL * 2 * 4);

    float* stats1 = stats;
    float* stats2 = stats + 72;

    // partials overlay B1..B2 (7.68 MB < 8.64 MB contiguous); fully consumed
    // by k_fill3 before conv1's first k_prop_gemm writes B1.
    int* partials = (int*)B1;   // [2][NB_H][NN]

    const int NBK = (NN + 63) / 64;
    const int CSB = 117;  // colstats grid: 117*256 = 29952, divisible by 36

    // ---- initial memset (gh+pcnt adjacent -> single fill; best inited in k_xc_score) ----
    hipMemsetAsync(gh, 0, 2 * 65536 * 4 + ((KSEL * 4 + 255) & ~255), stream);

    // ---- degree + CSR build (LDS histograms + rank; atomic-free fill) ----
    {
        dim3 gh2(NB_H, 2);
        k_hist<<<gh2, 1024, 0, stream>>>(src, dst, partials, rank);
        k_red<<<nb(NN), TPB, 0, stream>>>(partials, dinv, cnt_dst, stats);
        k_scan<<<1, 1024, 0, stream>>>(cnt_dst, rowstart, NN);
        k_fill3<<<nb(NE), TPB, 0, stream>>>(src, dst, rank, dinv, rowstart,
                                            partials + (size_t)NB_H * NN, csr, NE);
    }

    // ---- conv1: K=8, 16 -> 36 (first hop fused with W0 GEMM + bias) ----
    {
        float* rot[3] = {B1, B2, B3};
        k_prop_gemm<FIN, H1, 64, true, false><<<NBK, 64 * (FIN / 4), 0, stream>>>(
            rowstart, csr, x, nullptr, W1 + FIN * H1, W1, b1, B1, acc, NN);
        const float* t_prev = x; const float* t_cur = B1;
        for (int kk = 2; kk < KHOP; ++kk) {
            float* o = rot[(kk - 1) % 3];
            if (kk < KHOP - 1)
                k_prop_gemm<FIN, H1, 64, false, false><<<NBK, 64 * (FIN / 4), 0, stream>>>(
                    rowstart, csr, t_cur, t_prev, W1 + kk * FIN * H1, nullptr, nullptr, o, acc, NN);
            else
                k_prop_gemm<FIN, H1, 64, false, true><<<NBK, 64 * (FIN / 4), 0, stream>>>(
                    rowstart, csr, t_cur, t_prev, W1 + kk * FIN * H1, nullptr, nullptr, o, acc, NN);
            t_prev = t_cur; t_cur = o;
        }
        k_colstats<H1><<<CSB, TPB, 0, stream>>>(acc, stats1, NN);
        k_bn<H1><<<nb((long long)NN * H1), TPB, 0, stream>>>(acc, stats1, g1, be1, x1, NN);
    }

    // ---- conv2: K=8, 36 -> 36 (first hop fused) ----
    {
        float* rot[3] = {B1, B2, B3};
        k_prop_gemm<H1, H2, 64, true, false><<<NBK, 64 * (H1 / 4), 0, stream>>>(
            rowstart, csr, x1, nullptr, W2 + H1 * H2, W2, b2, B1, acc, NN);
        const float* t_prev = x1; const float* t_cur = B1;
        for (int kk = 2; kk < KHOP; ++kk) {
            float* o = rot[(kk - 1) % 3];
            if (kk < KHOP - 1)
                k_prop_gemm<H1, H2, 64, false, false><<<NBK, 64 * (H1 / 4), 0, stream>>>(
                    rowstart, csr, t_cur, t_prev, W2 + kk * H1 * H2, nullptr, nullptr, o, acc, NN);
            else
                k_prop_gemm<H1, H2, 64, false, true><<<NBK, 64 * (H1 / 4), 0, stream>>>(
                    rowstart, csr, t_cur, t_prev, W2 + kk * H1 * H2, nullptr, nullptr, o, acc, NN);
            t_prev = t_cur; t_cur = o;
        }
        k_colstats<H2><<<CSB, TPB, 0, stream>>>(acc, stats2, NN);
        k_bn<H2><<<nb((long long)NN * H2), TPB, 0, stream>>>(acc, stats2, g2, be2, x2, NN);
    }

    // ---- xc, score, key + first 16-bit histogram + best-init (fused) ----
    k_xc_score<<<nb(NN), TPB, 0, stream>>>(x1, Wc, bc, pw, xc, score, key, gh, best, NN);

    // ---- top-k threshold (parallel 2x16-bit radix) ----
    k_scanhist<<<1, 1024, 0, stream>>>(gh, nullptr, KSEL, nullptr, BinPtr, RemPtr);
    k_h16b<<<nb(NN), TPB, 0, stream>>>(key, BinPtr, gh + 65536, NN);
    k_scanhist<<<1, 1024, 0, stream>>>(gh + 65536, RemPtr, 0, BinPtr, Tptr, Rptr);

    // ---- parallel select (ascending-index order) ----
    {
        const int SB = (NN + 1023) / 1024;   // 30 blocks
        k_selcnt<<<SB, 1024, 0, stream>>>(key, Tptr, bgt, beq, NN);
        k_seloff<<<1, 64, 0, stream>>>(bgt, beq, Rptr, eqoff, soff, SB);
        k_selfill<<<SB, 1024, 0, stream>>>(key, Tptr, Rptr, eqoff, soff, nidx, sel, NN);
    }

    // ---- pooled graph build (parallel) ----
    {
        const int WPB = TPB / 64;
        const int GB = (KSEL + WPB - 1) / WPB;
        k_plen<<<GB, TPB, 0, stream>>>(rowstart, csr, nidx, sel, pcnt, lens);
        k_scan_pool<<<1, 1024, 0, stream>>>(lens, prs, pcnt, dinvp);
        k_pfill<<<GB, TPB, 0, stream>>>(rowstart, csr, nidx, sel, dinvp, prs, gcsr);
    }

    // ---- pooled 7-hop pipeline (LDS-resident) ----
    k_pooled4<<<1, 1024, 0, stream>>>(prs, gcsr, sel, xc, score, x, Wp, bp, pacc, selpos);

    // ---- nearest pooled node (chunked), final linear ----
    {
        dim3 g(nb(NN), NCHUNK);
        k_near_part<<<g, TPB, 0, stream>>>(x, selpos, best, NN);
    }
    k_final<<<nb((long long)NN * 10), TPB, 0, stream>>>(x1, x2, pacc, best, W3, b3, out, NN);
}